// Round 1
// baseline (2457.666 us; speedup 1.0000x reference)
//
#include <hip/hip_runtime.h>
#include <math.h>

#define S_ROWS 2047
#define DIM 256
#define HID 512
#define NHEADS 8
#define DH 32
#define NBINS 16
#define AFF_OUT 49
#define KSPLIT 4

// ---------------------------------------------------------------------------
// Generic f32 GEMM: C[N,M] = act(A[N,K] @ W[M,K]^T + bias + res)
// A row-major ld=K, W row-major (M,K) ld=K, C row-major ld=M.
// 64x64 C-tile per block, 256 threads, each 4x4. K-tiles of 16 staged
// transposed in LDS (pad 72 -> float4 fragment reads are aligned b128).
// ---------------------------------------------------------------------------
__global__ __launch_bounds__(256) void gemm_kernel(
    const float* __restrict__ A, const float* __restrict__ W,
    const float* __restrict__ bias, const float* __restrict__ res,
    float* __restrict__ C, int N, int M, int K, int relu)
{
    __shared__ float As[16][72];
    __shared__ float Ws[16][72];
    int tid = threadIdx.x;
    int tx = tid & 15, ty = tid >> 4;
    int row0 = blockIdx.y * 64, col0 = blockIdx.x * 64;
    int lrow = tid >> 2;           // 0..63
    int lk4  = (tid & 3) << 2;     // 0,4,8,12
    float acc[4][4];
    #pragma unroll
    for (int i = 0; i < 4; i++)
        #pragma unroll
        for (int j = 0; j < 4; j++) acc[i][j] = 0.f;

    for (int k0 = 0; k0 < K; k0 += 16) {
        int r = row0 + lrow;
        int c = col0 + lrow;
        #pragma unroll
        for (int j = 0; j < 4; j++) {
            int kk = k0 + lk4 + j;
            As[lk4 + j][lrow] = (r < N && kk < K) ? A[(size_t)r * K + kk] : 0.f;
            Ws[lk4 + j][lrow] = (c < M && kk < K) ? W[(size_t)c * K + kk] : 0.f;
        }
        __syncthreads();
        #pragma unroll
        for (int kk = 0; kk < 16; kk++) {
            float4 a4 = *(const float4*)&As[kk][ty << 2];
            float4 w4 = *(const float4*)&Ws[kk][tx << 2];
            float a[4] = {a4.x, a4.y, a4.z, a4.w};
            float w[4] = {w4.x, w4.y, w4.z, w4.w};
            #pragma unroll
            for (int i = 0; i < 4; i++)
                #pragma unroll
                for (int j = 0; j < 4; j++)
                    acc[i][j] += a[i] * w[j];
        }
        __syncthreads();
    }
    #pragma unroll
    for (int i = 0; i < 4; i++) {
        int r = row0 + (ty << 2) + i;
        if (r >= N) continue;
        #pragma unroll
        for (int j = 0; j < 4; j++) {
            int c = col0 + (tx << 2) + j;
            if (c >= M) continue;
            float v = acc[i][j];
            if (bias) v += bias[c];
            if (res)  v += res[(size_t)r * M + c];
            if (relu) v = fmaxf(v, 0.f);
            C[(size_t)r * M + c] = v;
        }
    }
}

// ---------------------------------------------------------------------------
// Flash attention, f32: grid (32 q-tiles, 8 heads, KSPLIT chunks), 64 thr.
// Each lane owns one query; online softmax over its key chunk; partials
// (m, l, acc[32]) written per (chunk, head, query).
// ---------------------------------------------------------------------------
__global__ __launch_bounds__(64) void attn_flash(
    const float* __restrict__ q, const float* __restrict__ kmat,
    const float* __restrict__ vmat, float* __restrict__ partial)
{
    __shared__ float ks[64 * 33];
    __shared__ float vs[64 * 33];
    int lane = threadIdx.x;
    int qidx = blockIdx.x * 64 + lane;
    int h = blockIdx.y;
    int ksp = blockIdx.z;
    bool active = qidx < S_ROWS;
    const float* qp = q + (size_t)(active ? qidx : 0) * DIM + h * DH;
    float qr[DH];
    #pragma unroll
    for (int d = 0; d < DH; d++) qr[d] = qp[d];
    float m = -1e30f, l = 0.f;
    float acc[DH];
    #pragma unroll
    for (int d = 0; d < DH; d++) acc[d] = 0.f;

    const int chunk = (S_ROWS + KSPLIT - 1) / KSPLIT;  // 512
    int t0 = ksp * chunk;
    int tend = min(t0 + chunk, S_ROWS);

    for (int tb = t0; tb < tend; tb += 64) {
        int t = tb + lane;
        if (t < tend) {
            const float4* kp = (const float4*)(kmat + (size_t)t * DIM + h * DH);
            const float4* vp = (const float4*)(vmat + (size_t)t * DIM + h * DH);
            #pragma unroll
            for (int j = 0; j < 8; j++) {
                float4 kv = kp[j], vv = vp[j];
                int b = lane * 33 + 4 * j;
                ks[b + 0] = kv.x; ks[b + 1] = kv.y; ks[b + 2] = kv.z; ks[b + 3] = kv.w;
                vs[b + 0] = vv.x; vs[b + 1] = vv.y; vs[b + 2] = vv.z; vs[b + 3] = vv.w;
            }
        } else {
            #pragma unroll
            for (int d = 0; d < DH; d++) { ks[lane * 33 + d] = 0.f; vs[lane * 33 + d] = 0.f; }
        }
        __syncthreads();
        int cnt = min(64, tend - tb);
        for (int j = 0; j < cnt; j++) {
            float s0 = 0.f, s1 = 0.f, s2 = 0.f, s3 = 0.f;
            #pragma unroll
            for (int d = 0; d < DH; d += 4) {
                s0 += qr[d + 0] * ks[j * 33 + d + 0];
                s1 += qr[d + 1] * ks[j * 33 + d + 1];
                s2 += qr[d + 2] * ks[j * 33 + d + 2];
                s3 += qr[d + 3] * ks[j * 33 + d + 3];
            }
            float s = ((s0 + s1) + (s2 + s3)) * 0.17677669529663687f;  // 1/sqrt(32)
            float mn = fmaxf(m, s);
            float corr = __expf(m - mn);
            float p = __expf(s - mn);
            l = l * corr + p;
            #pragma unroll
            for (int d = 0; d < DH; d++)
                acc[d] = acc[d] * corr + p * vs[j * 33 + d];
            m = mn;
        }
        __syncthreads();
    }
    if (active) {
        float* o = partial + ((size_t)(ksp * NHEADS + h) * 2048 + qidx) * 36;
        o[0] = m; o[1] = l;
        #pragma unroll
        for (int d = 0; d < DH; d++) o[2 + d] = acc[d];
    }
}

__global__ void attn_combine(const float* __restrict__ partial, float* __restrict__ o)
{
    int idx = blockIdx.x * blockDim.x + threadIdx.x;
    if (idx >= S_ROWS * NHEADS) return;
    int h = idx % NHEADS, qi = idx / NHEADS;
    float m = -1e30f;
    #pragma unroll
    for (int c = 0; c < KSPLIT; c++)
        m = fmaxf(m, partial[((size_t)(c * NHEADS + h) * 2048 + qi) * 36]);
    float l = 0.f;
    float num[DH];
    #pragma unroll
    for (int d = 0; d < DH; d++) num[d] = 0.f;
    #pragma unroll
    for (int c = 0; c < KSPLIT; c++) {
        const float* p = partial + ((size_t)(c * NHEADS + h) * 2048 + qi) * 36;
        float w = __expf(p[0] - m);
        l += p[1] * w;
        #pragma unroll
        for (int d = 0; d < DH; d++) num[d] += p[2 + d] * w;
    }
    float inv = 1.f / l;
    #pragma unroll
    for (int d = 0; d < DH; d++)
        o[(size_t)qi * DIM + h * DH + d] = num[d] * inv;
}

// ---------------------------------------------------------------------------
// cond features: [cos(x0*2pi*f), sin(x0*2pi*f), cos(x1..), sin(x1..), scale,
// temp, press] -> (2047, 35)
// ---------------------------------------------------------------------------
__global__ void embed_kernel(const float* __restrict__ pos,
    const float* __restrict__ scale, const float* __restrict__ press,
    const float* __restrict__ temp, float* __restrict__ cond)
{
    int i = blockIdx.x * blockDim.x + threadIdx.x;
    if (i >= S_ROWS * 35) return;
    int row = i / 35, c = i % 35;
    float v;
    if (c < 32) {
        int coord = c >> 4;     // 0 or 1
        int w = c & 15;         // 0..7 cos, 8..15 sin
        float x = pos[(row + 1) * 3 + coord];
        float f = 6.283185307179586f * (float)((w & 7) + 1);
        float ang = x * f;
        v = (w < 8) ? cosf(ang) : sinf(ang);
    } else if (c == 32) v = scale[0];
    else if (c == 33) v = temp[0];
    else v = press[0];
    cond[(size_t)row * 35 + c] = v;
}

__global__ void copy_pos(const float* __restrict__ pos, float* __restrict__ out)
{
    int i = blockIdx.x * blockDim.x + threadIdx.x;
    if (i < 6144) out[i] = pos[i];
}

// ---------------------------------------------------------------------------
// RQS spline: one thread per row (2047)
// ---------------------------------------------------------------------------
__global__ void spline_kernel(const float* __restrict__ pos,
    const float* __restrict__ params, float* __restrict__ out,
    float* __restrict__ ldp)
{
    int r = blockIdx.x * blockDim.x + threadIdx.x;
    if (r >= S_ROWS) return;
    const float* p = params + (size_t)r * AFF_OUT;
    float x = pos[(r + 1) * 3 + 2];

    float uw[NBINS], uh[NBINS];
    float mw = -1e30f, mh = -1e30f;
    #pragma unroll
    for (int j = 0; j < NBINS; j++) {
        uw[j] = p[j];         mw = fmaxf(mw, uw[j]);
        uh[j] = p[NBINS + j]; mh = fmaxf(mh, uh[j]);
    }
    float sw = 0.f, sh = 0.f;
    #pragma unroll
    for (int j = 0; j < NBINS; j++) {
        uw[j] = __expf(uw[j] - mw); sw += uw[j];
        uh[j] = __expf(uh[j] - mh); sh += uh[j];
    }
    const float span = 1.0f - NBINS * 1e-4f;
    float scw = span / sw, sch = span / sh;

    float xpos[NBINS + 1], ypos[NBINS + 1];
    xpos[0] = 0.f; ypos[0] = 0.f;
    #pragma unroll
    for (int j = 0; j < NBINS; j++) {
        xpos[j + 1] = xpos[j] + (uw[j] * scw + 1e-4f);
        ypos[j + 1] = ypos[j] + (uh[j] * sch + 1e-4f);
    }
    float offset = logf(expm1f(0.9999f));
    float slopes[NBINS + 1];
    #pragma unroll
    for (int j = 0; j <= NBINS; j++) {
        float raw = (j < NBINS) ? p[2 * NBINS + j] : p[2 * NBINS];
        float t = raw + offset;
        slopes[j] = ((t > 15.f) ? t : log1pf(__expf(t))) + 1e-4f;
    }
    float xc = fminf(fmaxf(x, 0.f), 1.f);
    int k = 0;
    #pragma unroll
    for (int j = 1; j < NBINS; j++) if (xc >= xpos[j]) k = j;
    float xk = xpos[k], xk1 = xpos[k + 1];
    float yk = ypos[k], yk1 = ypos[k + 1];
    float dk = slopes[k], dk1 = slopes[k + 1];
    float w = xk1 - xk, hh = yk1 - yk;
    float sl = hh / w;
    float z = (xc - xk) / w;
    float z1 = 1.f - z;
    float den = sl + (dk1 + dk - 2.f * sl) * z * z1;
    float y = yk + hh * (sl * z * z + dk * z * z1) / den;
    float ld = 2.f * logf(sl) + logf(dk1 * z * z + 2.f * sl * z * z1 + dk * z1 * z1)
               - 2.f * logf(den);
    bool inside = (x >= 0.f) && (x <= 1.f);
    y = inside ? y : x;
    ld = inside ? ld : 0.f;
    out[(r + 1) * 3 + 2] = y;
    ldp[r] = ld;
}

__global__ void reduce_kernel(const float* __restrict__ ldp, float* __restrict__ out)
{
    __shared__ float sh[256];
    int tid = threadIdx.x;
    float s = 0.f;
    for (int i = tid; i < S_ROWS; i += 256) s += ldp[i];
    sh[tid] = s;
    __syncthreads();
    for (int st = 128; st > 0; st >>= 1) {
        if (tid < st) sh[tid] += sh[tid + st];
        __syncthreads();
    }
    if (tid == 0) out[6144] = sh[0];
}

// ---------------------------------------------------------------------------
extern "C" void kernel_launch(void* const* d_in, const int* in_sizes, int n_in,
                              void* d_out, int out_size, void* d_ws, size_t ws_size,
                              hipStream_t stream)
{
    const float* pos   = (const float*)d_in[0];
    const float* scale = (const float*)d_in[1];
    const float* press = (const float*)d_in[2];
    const float* temp  = (const float*)d_in[3];
    const float* e_w0  = (const float*)d_in[4];
    const float* e_b0  = (const float*)d_in[5];
    const float* e_w1  = (const float*)d_in[6];
    const float* e_b1  = (const float*)d_in[7];
    const float* e_w2  = (const float*)d_in[8];
    const float* e_b2  = (const float*)d_in[9];
    const float* Wq    = (const float*)d_in[10];
    const float* Wk    = (const float*)d_in[11];
    const float* bk    = (const float*)d_in[12];
    const float* Wv    = (const float*)d_in[13];
    const float* Wo    = (const float*)d_in[14];
    const float* bo    = (const float*)d_in[15];
    const float* mw0   = (const float*)d_in[16];
    const float* mb0   = (const float*)d_in[17];
    const float* mw1   = (const float*)d_in[18];
    const float* mb1   = (const float*)d_in[19];
    const float* mw2   = (const float*)d_in[20];
    const float* mb2   = (const float*)d_in[21];
    const float* a_w0  = (const float*)d_in[22];
    const float* a_b0  = (const float*)d_in[23];
    const float* a_w1  = (const float*)d_in[24];
    const float* a_b1  = (const float*)d_in[25];
    const float* a_w2  = (const float*)d_in[26];
    const float* a_b2  = (const float*)d_in[27];
    float* out = (float*)d_out;

    float* ws = (float*)d_ws;
    size_t off = 0;
    float* cond = ws + off; off += 2048 * 35;
    float* t1   = ws + off; off += 2048 * 512;
    float* t2   = ws + off; off += 2048 * 512;
    float* hbuf = ws + off; off += 2048 * 256;
    float* qb   = ws + off; off += 2048 * 256;
    float* kb   = ws + off; off += 2048 * 256;
    float* vb   = ws + off; off += 2048 * 256;
    float* ob   = ws + off; off += 2048 * 256;
    float* part = ws + off; off += (size_t)KSPLIT * NHEADS * 2048 * 36;
    float* pr   = ws + off; off += 2048 * AFF_OUT;
    float* ldp  = ws + off; off += 2048;

    dim3 b256(256);
    hipLaunchKernelGGL(embed_kernel, dim3((S_ROWS * 35 + 255) / 256), b256, 0, stream,
                       pos, scale, press, temp, cond);
    hipLaunchKernelGGL(copy_pos, dim3(24), b256, 0, stream, pos, out);

    auto gemm = [&](const float* A, const float* W, const float* bias,
                    const float* res, float* C, int N, int M, int K, int relu) {
        dim3 grid((M + 63) / 64, (N + 63) / 64);
        hipLaunchKernelGGL(gemm_kernel, grid, dim3(256), 0, stream,
                           A, W, bias, res, C, N, M, K, relu);
    };

    // embedding MLP: 35 -> 512 -> 512 -> 256
    gemm(cond, e_w0, e_b0, nullptr, t1, S_ROWS, 512, 35, 1);
    gemm(t1,   e_w1, e_b1, nullptr, t2, S_ROWS, 512, 512, 1);
    gemm(t2,   e_w2, e_b2, nullptr, hbuf, S_ROWS, 256, 512, 0);

    for (int l = 0; l < 4; l++) {
        const float* wq = Wq + (size_t)l * 65536;
        const float* wk = Wk + (size_t)l * 65536;
        const float* wv = Wv + (size_t)l * 65536;
        const float* wo = Wo + (size_t)l * 65536;
        gemm(hbuf, wq, nullptr,      nullptr, qb, S_ROWS, 256, 256, 0);
        gemm(hbuf, wk, bk + l * 256, nullptr, kb, S_ROWS, 256, 256, 0);
        gemm(hbuf, wv, nullptr,      nullptr, vb, S_ROWS, 256, 256, 0);
        hipLaunchKernelGGL(attn_flash, dim3(32, NHEADS, KSPLIT), dim3(64), 0, stream,
                           qb, kb, vb, part);
        hipLaunchKernelGGL(attn_combine, dim3((S_ROWS * NHEADS + 255) / 256), b256,
                           0, stream, part, ob);
        gemm(ob, wo, bo + l * 256, hbuf, hbuf, S_ROWS, 256, 256, 0);  // residual add
        gemm(hbuf, mw0 + (size_t)l * 131072, mb0 + l * 512, nullptr, t1, S_ROWS, 512, 256, 1);
        gemm(t1,   mw1 + (size_t)l * 262144, mb1 + l * 512, nullptr, t2, S_ROWS, 512, 512, 1);
        gemm(t2,   mw2 + (size_t)l * 131072, mb2 + l * 256, hbuf,    hbuf, S_ROWS, 256, 512, 0);
    }

    // affine-param MLP: 256 -> 512 -> 512 -> 49
    gemm(hbuf, a_w0, a_b0, nullptr, t1, S_ROWS, 512, 256, 1);
    gemm(t1,   a_w1, a_b1, nullptr, t2, S_ROWS, 512, 512, 1);
    gemm(t2,   a_w2, a_b2, nullptr, pr, S_ROWS, AFF_OUT, 512, 0);

    hipLaunchKernelGGL(spline_kernel, dim3((S_ROWS + 255) / 256), b256, 0, stream,
                       pos, pr, out, ldp);
    hipLaunchKernelGGL(reduce_kernel, dim3(1), b256, 0, stream, ldp, out);
}

// Round 2
// 1058.695 us; speedup vs baseline: 2.3214x; 2.3214x over previous
//
#include <hip/hip_runtime.h>
#include <math.h>

#define S_ROWS 2047
#define DIM 256
#define HID 512
#define NHEADS 8
#define DH 32
#define NBINS 16
#define AFF_OUT 49

typedef short bf16x8 __attribute__((ext_vector_type(8)));
typedef float f32x4 __attribute__((ext_vector_type(4)));
typedef unsigned short u16x8 __attribute__((ext_vector_type(8)));
typedef unsigned short u16x4 __attribute__((ext_vector_type(4)));

__device__ inline unsigned short f2b(float f) {
    unsigned int u = __float_as_uint(f);
    u += 0x7FFFu + ((u >> 16) & 1u);      // round-to-nearest-even
    return (unsigned short)(u >> 16);
}

// ---------------------------------------------------------------------------
// Weight conversion f32 -> bf16, all tensors concatenated into one ws region.
// Segment offsets are compile-time constants; every size is a multiple of 4.
// ---------------------------------------------------------------------------
#define W_TOTAL 3975168
__global__ __launch_bounds__(256) void convert_weights(
    const float* __restrict__ p0, const float* __restrict__ p1,
    const float* __restrict__ p2, const float* __restrict__ p3,
    const float* __restrict__ p4, const float* __restrict__ p5,
    const float* __restrict__ p6, const float* __restrict__ p7,
    const float* __restrict__ p8, const float* __restrict__ p9,
    const float* __restrict__ p10, const float* __restrict__ p11,
    const float* __restrict__ p12, unsigned short* __restrict__ dst)
{
    const int offs[14] = {0, 17920, 280064, 411136, 673280, 935424, 1197568,
                          1459712, 1984000, 3032576, 3556864, 3687936, 3950080,
                          3975168};
    const float* srcs[13] = {p0,p1,p2,p3,p4,p5,p6,p7,p8,p9,p10,p11,p12};
    int n4 = W_TOTAL / 4;
    for (int i4 = blockIdx.x * blockDim.x + threadIdx.x; i4 < n4;
         i4 += gridDim.x * blockDim.x) {
        int e = i4 * 4;
        int s = 0;
        #pragma unroll
        for (int j = 1; j < 13; j++) s += (e >= offs[j]);
        const float4 v = *(const float4*)(srcs[s] + (e - offs[s]));
        u16x4 o;
        o[0] = f2b(v.x); o[1] = f2b(v.y); o[2] = f2b(v.z); o[3] = f2b(v.w);
        *(u16x4*)(dst + e) = o;
    }
}

// ---------------------------------------------------------------------------
// bf16 MFMA GEMM: C[N,M] = act(A[N,K] @ W[M,K]^T + bias + res)
// A f32 (converted to bf16 during staging), W bf16 pre-converted.
// 64x64 C-tile, 256 thr = 4 waves; wave w computes rows [16w,16w+16) x 64.
// mfma_f32_16x16x32_bf16; frag maps per m89/m91 verified layout.
// ---------------------------------------------------------------------------
#define LDK 72
__global__ __launch_bounds__(256, 2) void gemm_bf16(
    const float* __restrict__ A, const unsigned short* __restrict__ W,
    const float* __restrict__ bias, const float* res,
    float* C, int N, int M, int K, int relu)
{
    __shared__ unsigned short As[64][LDK];
    __shared__ unsigned short Bs[64][LDK];
    int tid = threadIdx.x;
    int wave = tid >> 6, lane = tid & 63;
    int quad = lane >> 4, l16 = lane & 15;
    int row0 = blockIdx.y << 6, col0 = blockIdx.x << 6;
    int srow = tid >> 2, scol = (tid & 3) << 4;

    f32x4 acc[4];
    #pragma unroll
    for (int i = 0; i < 4; i++) { f32x4 z = {0.f,0.f,0.f,0.f}; acc[i] = z; }

    for (int k0 = 0; k0 < K; k0 += 64) {
        // ---- stage A (f32 -> bf16) ----
        {
            int ar = row0 + srow;
            unsigned short tmp[16];
            if (ar < N && k0 + 64 <= K) {
                const float4* ap = (const float4*)(A + (size_t)ar * K + k0 + scol);
                #pragma unroll
                for (int j = 0; j < 4; j++) {
                    float4 v = ap[j];
                    tmp[4*j+0] = f2b(v.x); tmp[4*j+1] = f2b(v.y);
                    tmp[4*j+2] = f2b(v.z); tmp[4*j+3] = f2b(v.w);
                }
            } else {
                #pragma unroll
                for (int j = 0; j < 16; j++) {
                    int kk = k0 + scol + j;
                    tmp[j] = (ar < N && kk < K) ? f2b(A[(size_t)ar * K + kk])
                                                : (unsigned short)0;
                }
            }
            *(u16x8*)&As[srow][scol]     = *(u16x8*)&tmp[0];
            *(u16x8*)&As[srow][scol + 8] = *(u16x8*)&tmp[8];
        }
        // ---- stage W (already bf16) ----
        {
            int wr = col0 + srow;
            if (wr < M && k0 + 64 <= K) {
                const u16x8* wp = (const u16x8*)(W + (size_t)wr * K + k0 + scol);
                *(u16x8*)&Bs[srow][scol]     = wp[0];
                *(u16x8*)&Bs[srow][scol + 8] = wp[1];
            } else {
                unsigned short tmp[16];
                #pragma unroll
                for (int j = 0; j < 16; j++) {
                    int kk = k0 + scol + j;
                    tmp[j] = (wr < M && kk < K) ? W[(size_t)wr * K + kk]
                                                : (unsigned short)0;
                }
                *(u16x8*)&Bs[srow][scol]     = *(u16x8*)&tmp[0];
                *(u16x8*)&Bs[srow][scol + 8] = *(u16x8*)&tmp[8];
            }
        }
        __syncthreads();
        #pragma unroll
        for (int kt = 0; kt < 64; kt += 32) {
            bf16x8 af = *(bf16x8*)&As[(wave << 4) + l16][kt + (quad << 3)];
            #pragma unroll
            for (int n0 = 0; n0 < 4; n0++) {
                bf16x8 bf = *(bf16x8*)&Bs[(n0 << 4) + l16][kt + (quad << 3)];
                acc[n0] = __builtin_amdgcn_mfma_f32_16x16x32_bf16(af, bf, acc[n0], 0, 0, 0);
            }
        }
        __syncthreads();
    }
    // ---- epilogue: C[row][col], col=lane&15, row=quad*4+reg ----
    #pragma unroll
    for (int n0 = 0; n0 < 4; n0++) {
        int col = col0 + (n0 << 4) + l16;
        if (col >= M) continue;
        float bv = bias ? bias[col] : 0.f;
        #pragma unroll
        for (int r = 0; r < 4; r++) {
            int row = row0 + (wave << 4) + (quad << 2) + r;
            if (row >= N) continue;
            float v = acc[n0][r] + bv;
            if (res) v += res[(size_t)row * M + col];
            if (relu) v = fmaxf(v, 0.f);
            C[(size_t)row * M + col] = v;
        }
    }
}

// ---------------------------------------------------------------------------
// Flash attention, f32, float4 LDS reads + rare-rescale online softmax.
// grid (32 q-tiles, 8 heads, ksplit chunks), 64 thr; 1 query per lane.
// ---------------------------------------------------------------------------
__global__ __launch_bounds__(64) void attn_flash(
    const float* __restrict__ q, const float* __restrict__ kmat,
    const float* __restrict__ vmat, float* __restrict__ partial, int ksplit)
{
    __shared__ float ks[64 * 36];
    __shared__ float vs[64 * 36];
    int lane = threadIdx.x;
    int qidx = blockIdx.x * 64 + lane;
    int h = blockIdx.y;
    int ksp = blockIdx.z;
    bool active = qidx < S_ROWS;
    const float4* qp = (const float4*)(q + (size_t)(active ? qidx : 0) * DIM + h * DH);
    float4 qr[8];
    #pragma unroll
    for (int j = 0; j < 8; j++) qr[j] = qp[j];
    float m = -1e30f, l = 0.f;
    float4 acc[8];
    #pragma unroll
    for (int j = 0; j < 8; j++) { float4 z = {0.f,0.f,0.f,0.f}; acc[j] = z; }

    int chunk = (S_ROWS + ksplit - 1) / ksplit;
    int t0 = ksp * chunk;
    int tend = min(t0 + chunk, S_ROWS);

    for (int tb = t0; tb < tend; tb += 64) {
        int t = tb + lane;
        if (t < tend) {
            const float4* kp = (const float4*)(kmat + (size_t)t * DIM + h * DH);
            const float4* vp = (const float4*)(vmat + (size_t)t * DIM + h * DH);
            float4* kd = (float4*)&ks[lane * 36];
            float4* vd = (float4*)&vs[lane * 36];
            #pragma unroll
            for (int j = 0; j < 8; j++) { kd[j] = kp[j]; vd[j] = vp[j]; }
        }
        __syncthreads();
        int cnt = min(64, tend - tb);
        for (int j = 0; j < cnt; j++) {
            const float4* kr = (const float4*)&ks[j * 36];
            float s0 = 0.f, s1 = 0.f, s2 = 0.f, s3 = 0.f;
            #pragma unroll
            for (int jj = 0; jj < 8; jj++) {
                float4 kv = kr[jj];
                s0 = fmaf(qr[jj].x, kv.x, s0);
                s1 = fmaf(qr[jj].y, kv.y, s1);
                s2 = fmaf(qr[jj].z, kv.z, s2);
                s3 = fmaf(qr[jj].w, kv.w, s3);
            }
            float s = ((s0 + s1) + (s2 + s3)) * 0.17677669529663687f; // 1/sqrt(32)
            const float4* vr = (const float4*)&vs[j * 36];
            if (s > m) {
                float corr = __expf(m - s);
                m = s;
                l = l * corr + 1.f;
                #pragma unroll
                for (int jj = 0; jj < 8; jj++) {
                    float4 vv = vr[jj];
                    acc[jj].x = fmaf(acc[jj].x, corr, vv.x);
                    acc[jj].y = fmaf(acc[jj].y, corr, vv.y);
                    acc[jj].z = fmaf(acc[jj].z, corr, vv.z);
                    acc[jj].w = fmaf(acc[jj].w, corr, vv.w);
                }
            } else {
                float p = __expf(s - m);
                l += p;
                #pragma unroll
                for (int jj = 0; jj < 8; jj++) {
                    float4 vv = vr[jj];
                    acc[jj].x = fmaf(p, vv.x, acc[jj].x);
                    acc[jj].y = fmaf(p, vv.y, acc[jj].y);
                    acc[jj].z = fmaf(p, vv.z, acc[jj].z);
                    acc[jj].w = fmaf(p, vv.w, acc[jj].w);
                }
            }
        }
        __syncthreads();
    }
    if (active) {
        float* o = partial + ((size_t)(ksp * NHEADS + h) * 2048 + qidx) * 36;
        o[0] = m; o[1] = l;
        #pragma unroll
        for (int j = 0; j < 8; j++) *(float4*)(o + 2 + 4 * j) = acc[j];
    }
}

__global__ void attn_combine(const float* __restrict__ partial,
                             float* __restrict__ o, int ksplit)
{
    int idx = blockIdx.x * blockDim.x + threadIdx.x;
    if (idx >= S_ROWS * NHEADS) return;
    int h = idx % NHEADS, qi = idx / NHEADS;
    float m = -1e30f;
    for (int c = 0; c < ksplit; c++)
        m = fmaxf(m, partial[((size_t)(c * NHEADS + h) * 2048 + qi) * 36]);
    float l = 0.f;
    float num[DH];
    #pragma unroll
    for (int d = 0; d < DH; d++) num[d] = 0.f;
    for (int c = 0; c < ksplit; c++) {
        const float* p = partial + ((size_t)(c * NHEADS + h) * 2048 + qi) * 36;
        float w = __expf(p[0] - m);
        l += p[1] * w;
        #pragma unroll
        for (int d = 0; d < DH; d++) num[d] = fmaf(p[2 + d], w, num[d]);
    }
    float inv = 1.f / l;
    #pragma unroll
    for (int d = 0; d < DH; d++)
        o[(size_t)qi * DIM + h * DH + d] = num[d] * inv;
}

// ---------------------------------------------------------------------------
__global__ void embed_kernel(const float* __restrict__ pos,
    const float* __restrict__ scale, const float* __restrict__ press,
    const float* __restrict__ temp, float* __restrict__ cond)
{
    int i = blockIdx.x * blockDim.x + threadIdx.x;
    if (i >= S_ROWS * 35) return;
    int row = i / 35, c = i % 35;
    float v;
    if (c < 32) {
        int coord = c >> 4;
        int w = c & 15;
        float x = pos[(row + 1) * 3 + coord];
        float f = 6.283185307179586f * (float)((w & 7) + 1);
        float ang = x * f;
        v = (w < 8) ? cosf(ang) : sinf(ang);
    } else if (c == 32) v = scale[0];
    else if (c == 33) v = temp[0];
    else v = press[0];
    cond[(size_t)row * 35 + c] = v;
}

__global__ void copy_pos(const float* __restrict__ pos, float* __restrict__ out)
{
    int i = blockIdx.x * blockDim.x + threadIdx.x;
    if (i < 6144) out[i] = pos[i];
}

// ---------------------------------------------------------------------------
__global__ void spline_kernel(const float* __restrict__ pos,
    const float* __restrict__ params, float* __restrict__ out,
    float* __restrict__ ldp)
{
    int r = blockIdx.x * blockDim.x + threadIdx.x;
    if (r >= S_ROWS) return;
    const float* p = params + (size_t)r * AFF_OUT;
    float x = pos[(r + 1) * 3 + 2];

    float uw[NBINS], uh[NBINS];
    float mw = -1e30f, mh = -1e30f;
    #pragma unroll
    for (int j = 0; j < NBINS; j++) {
        uw[j] = p[j];         mw = fmaxf(mw, uw[j]);
        uh[j] = p[NBINS + j]; mh = fmaxf(mh, uh[j]);
    }
    float sw = 0.f, sh = 0.f;
    #pragma unroll
    for (int j = 0; j < NBINS; j++) {
        uw[j] = __expf(uw[j] - mw); sw += uw[j];
        uh[j] = __expf(uh[j] - mh); sh += uh[j];
    }
    const float span = 1.0f - NBINS * 1e-4f;
    float scw = span / sw, sch = span / sh;

    float xpos[NBINS + 1], ypos[NBINS + 1];
    xpos[0] = 0.f; ypos[0] = 0.f;
    #pragma unroll
    for (int j = 0; j < NBINS; j++) {
        xpos[j + 1] = xpos[j] + (uw[j] * scw + 1e-4f);
        ypos[j + 1] = ypos[j] + (uh[j] * sch + 1e-4f);
    }
    float offset = logf(expm1f(0.9999f));
    float slopes[NBINS + 1];
    #pragma unroll
    for (int j = 0; j <= NBINS; j++) {
        float raw = (j < NBINS) ? p[2 * NBINS + j] : p[2 * NBINS];
        float t = raw + offset;
        slopes[j] = ((t > 15.f) ? t : log1pf(__expf(t))) + 1e-4f;
    }
    float xc = fminf(fmaxf(x, 0.f), 1.f);
    int k = 0;
    #pragma unroll
    for (int j = 1; j < NBINS; j++) if (xc >= xpos[j]) k = j;
    float xk = xpos[k], xk1 = xpos[k + 1];
    float yk = ypos[k], yk1 = ypos[k + 1];
    float dk = slopes[k], dk1 = slopes[k + 1];
    float w = xk1 - xk, hh = yk1 - yk;
    float sl = hh / w;
    float z = (xc - xk) / w;
    float z1 = 1.f - z;
    float den = sl + (dk1 + dk - 2.f * sl) * z * z1;
    float y = yk + hh * (sl * z * z + dk * z * z1) / den;
    float ld = 2.f * logf(sl) + logf(dk1 * z * z + 2.f * sl * z * z1 + dk * z1 * z1)
               - 2.f * logf(den);
    bool inside = (x >= 0.f) && (x <= 1.f);
    y = inside ? y : x;
    ld = inside ? ld : 0.f;
    out[(r + 1) * 3 + 2] = y;
    ldp[r] = ld;
}

__global__ void reduce_kernel(const float* __restrict__ ldp, float* __restrict__ out)
{
    __shared__ float sh[256];
    int tid = threadIdx.x;
    float s = 0.f;
    for (int i = tid; i < S_ROWS; i += 256) s += ldp[i];
    sh[tid] = s;
    __syncthreads();
    for (int st = 128; st > 0; st >>= 1) {
        if (tid < st) sh[tid] += sh[tid + st];
        __syncthreads();
    }
    if (tid == 0) out[6144] = sh[0];
}

// ---------------------------------------------------------------------------
extern "C" void kernel_launch(void* const* d_in, const int* in_sizes, int n_in,
                              void* d_out, int out_size, void* d_ws, size_t ws_size,
                              hipStream_t stream)
{
    const float* pos   = (const float*)d_in[0];
    const float* scale = (const float*)d_in[1];
    const float* press = (const float*)d_in[2];
    const float* temp  = (const float*)d_in[3];
    const float* e_w0  = (const float*)d_in[4];
    const float* e_b0  = (const float*)d_in[5];
    const float* e_w1  = (const float*)d_in[6];
    const float* e_b1  = (const float*)d_in[7];
    const float* e_w2  = (const float*)d_in[8];
    const float* e_b2  = (const float*)d_in[9];
    const float* Wq    = (const float*)d_in[10];
    const float* Wk    = (const float*)d_in[11];
    const float* bk    = (const float*)d_in[12];
    const float* Wv    = (const float*)d_in[13];
    const float* Wo    = (const float*)d_in[14];
    const float* bo    = (const float*)d_in[15];
    const float* mw0   = (const float*)d_in[16];
    const float* mb0   = (const float*)d_in[17];
    const float* mw1   = (const float*)d_in[18];
    const float* mb1   = (const float*)d_in[19];
    const float* mw2   = (const float*)d_in[20];
    const float* mb2   = (const float*)d_in[21];
    const float* a_w0  = (const float*)d_in[22];
    const float* a_b0  = (const float*)d_in[23];
    const float* a_w1  = (const float*)d_in[24];
    const float* a_b1  = (const float*)d_in[25];
    const float* a_w2  = (const float*)d_in[26];
    const float* a_b2  = (const float*)d_in[27];
    float* out = (float*)d_out;

    // weight-segment offsets (elements) in the bf16 region
    enum { OFF_EW0 = 0, OFF_EW1 = 17920, OFF_EW2 = 280064, OFF_WQ = 411136,
           OFF_WK = 673280, OFF_WV = 935424, OFF_WO = 1197568, OFF_MW0 = 1459712,
           OFF_MW1 = 1984000, OFF_MW2 = 3032576, OFF_AW0 = 3556864,
           OFF_AW1 = 3687936, OFF_AW2 = 3950080 };

    float* ws = (float*)d_ws;
    size_t off = 0;
    float* cond = ws + off; off += 2048 * 35;
    float* t1   = ws + off; off += 2048 * 512;
    float* t2   = ws + off; off += 2048 * 512;
    float* hbuf = ws + off; off += 2048 * 256;
    float* qb   = ws + off; off += 2048 * 256;
    float* kb   = ws + off; off += 2048 * 256;
    float* vb   = ws + off; off += 2048 * 256;
    float* ob   = ws + off; off += 2048 * 256;
    float* pr   = ws + off; off += 2048 * 64;
    float* ldp  = ws + off; off += 2048;
    unsigned short* wb = (unsigned short*)(ws + off); off += (W_TOTAL + 1) / 2;
    float* part = ws + off;  // ksplit*8*2048*36 floats

    size_t base_bytes = off * 4;
    int ksplit = (ws_size >= base_bytes + (size_t)8 * 8 * 2048 * 36 * 4) ? 8 : 4;

    dim3 b256(256);
    hipLaunchKernelGGL(convert_weights, dim3(1024), b256, 0, stream,
                       e_w0, e_w1, e_w2, Wq, Wk, Wv, Wo, mw0, mw1, mw2,
                       a_w0, a_w1, a_w2, wb);
    hipLaunchKernelGGL(embed_kernel, dim3((S_ROWS * 35 + 255) / 256), b256, 0, stream,
                       pos, scale, press, temp, cond);
    hipLaunchKernelGGL(copy_pos, dim3(24), b256, 0, stream, pos, out);

    auto gemm = [&](const float* A, const unsigned short* W, const float* bias,
                    const float* res, float* C, int N, int M, int K, int relu) {
        dim3 grid((M + 63) / 64, (N + 63) / 64);
        hipLaunchKernelGGL(gemm_bf16, grid, dim3(256), 0, stream,
                           A, W, bias, res, C, N, M, K, relu);
    };

    // embedding MLP: 35 -> 512 -> 512 -> 256
    gemm(cond, wb + OFF_EW0, e_b0, nullptr, t1, S_ROWS, 512, 35, 1);
    gemm(t1,   wb + OFF_EW1, e_b1, nullptr, t2, S_ROWS, 512, 512, 1);
    gemm(t2,   wb + OFF_EW2, e_b2, nullptr, hbuf, S_ROWS, 256, 512, 0);

    for (int l = 0; l < 4; l++) {
        gemm(hbuf, wb + OFF_WQ + l * 65536, nullptr,      nullptr, qb, S_ROWS, 256, 256, 0);
        gemm(hbuf, wb + OFF_WK + l * 65536, bk + l * 256, nullptr, kb, S_ROWS, 256, 256, 0);
        gemm(hbuf, wb + OFF_WV + l * 65536, nullptr,      nullptr, vb, S_ROWS, 256, 256, 0);
        hipLaunchKernelGGL(attn_flash, dim3(32, NHEADS, ksplit), dim3(64), 0, stream,
                           qb, kb, vb, part, ksplit);
        hipLaunchKernelGGL(attn_combine, dim3((S_ROWS * NHEADS + 255) / 256), b256,
                           0, stream, part, ob, ksplit);
        gemm(ob, wb + OFF_WO + l * 65536, bo + l * 256, hbuf, hbuf, S_ROWS, 256, 256, 0);
        gemm(hbuf, wb + OFF_MW0 + l * 131072, mb0 + l * 512, nullptr, t1, S_ROWS, 512, 256, 1);
        gemm(t1,   wb + OFF_MW1 + l * 262144, mb1 + l * 512, nullptr, t2, S_ROWS, 512, 512, 1);
        gemm(t2,   wb + OFF_MW2 + l * 131072, mb2 + l * 256, hbuf,    hbuf, S_ROWS, 256, 512, 0);
    }

    // affine-param MLP: 256 -> 512 -> 512 -> 49
    gemm(hbuf, wb + OFF_AW0, a_b0, nullptr, t1, S_ROWS, 512, 256, 1);
    gemm(t1,   wb + OFF_AW1, a_b1, nullptr, t2, S_ROWS, 512, 512, 1);
    gemm(t2,   wb + OFF_AW2, a_b2, nullptr, pr, S_ROWS, AFF_OUT, 512, 0);

    hipLaunchKernelGGL(spline_kernel, dim3((S_ROWS + 255) / 256), b256, 0, stream,
                       pos, pr, out, ldp);
    hipLaunchKernelGGL(reduce_kernel, dim3(1), b256, 0, stream, ldp, out);
}

// Round 3
// 582.603 us; speedup vs baseline: 4.2184x; 1.8172x over previous
//
#include <hip/hip_runtime.h>
#include <math.h>

#define S_ROWS 2047
#define DIM 256
#define HID 512
#define NHEADS 8
#define DH 32
#define NBINS 16
#define AFF_OUT 49
#define KCHUNKS 4

typedef short bf16x8 __attribute__((ext_vector_type(8)));
typedef float f32x4 __attribute__((ext_vector_type(4)));
typedef float f32x16 __attribute__((ext_vector_type(16)));
typedef unsigned short u16x8 __attribute__((ext_vector_type(8)));
typedef unsigned short u16x4 __attribute__((ext_vector_type(4)));

__device__ inline unsigned short f2b(float f) {
    unsigned int u = __float_as_uint(f);
    u += 0x7FFFu + ((u >> 16) & 1u);      // round-to-nearest-even
    return (unsigned short)(u >> 16);
}

// ---------------------------------------------------------------------------
// Weight conversion f32 -> bf16 (one packed region).
// ---------------------------------------------------------------------------
#define W_TOTAL 3975168
__global__ __launch_bounds__(256) void convert_weights(
    const float* __restrict__ p0, const float* __restrict__ p1,
    const float* __restrict__ p2, const float* __restrict__ p3,
    const float* __restrict__ p4, const float* __restrict__ p5,
    const float* __restrict__ p6, const float* __restrict__ p7,
    const float* __restrict__ p8, const float* __restrict__ p9,
    const float* __restrict__ p10, const float* __restrict__ p11,
    const float* __restrict__ p12, unsigned short* __restrict__ dst)
{
    const int offs[14] = {0, 17920, 280064, 411136, 673280, 935424, 1197568,
                          1459712, 1984000, 3032576, 3556864, 3687936, 3950080,
                          3975168};
    const float* srcs[13] = {p0,p1,p2,p3,p4,p5,p6,p7,p8,p9,p10,p11,p12};
    int n4 = W_TOTAL / 4;
    for (int i4 = blockIdx.x * blockDim.x + threadIdx.x; i4 < n4;
         i4 += gridDim.x * blockDim.x) {
        int e = i4 * 4;
        int s = 0;
        #pragma unroll
        for (int j = 1; j < 13; j++) s += (e >= offs[j]);
        const float4 v = *(const float4*)(srcs[s] + (e - offs[s]));
        u16x4 o;
        o[0] = f2b(v.x); o[1] = f2b(v.y); o[2] = f2b(v.z); o[3] = f2b(v.w);
        *(u16x4*)(dst + e) = o;
    }
}

// ---------------------------------------------------------------------------
// Generic bf16 MFMA GEMM: C[N,M] = act(A[N,K] @ W[M,K]^T + bias + res)
// ---------------------------------------------------------------------------
#define LDK 72
__global__ __launch_bounds__(256, 2) void gemm_bf16(
    const float* __restrict__ A, const unsigned short* __restrict__ W,
    const float* __restrict__ bias, const float* res,
    float* C, int N, int M, int K, int relu)
{
    __shared__ unsigned short As[64][LDK];
    __shared__ unsigned short Bs[64][LDK];
    int tid = threadIdx.x;
    int wave = tid >> 6, lane = tid & 63;
    int quad = lane >> 4, l16 = lane & 15;
    int row0 = blockIdx.y << 6, col0 = blockIdx.x << 6;
    int srow = tid >> 2, scol = (tid & 3) << 4;

    f32x4 acc[4];
    #pragma unroll
    for (int i = 0; i < 4; i++) { f32x4 z = {0.f,0.f,0.f,0.f}; acc[i] = z; }

    for (int k0 = 0; k0 < K; k0 += 64) {
        {
            int ar = row0 + srow;
            unsigned short tmp[16];
            if (ar < N && k0 + 64 <= K) {
                const float4* ap = (const float4*)(A + (size_t)ar * K + k0 + scol);
                #pragma unroll
                for (int j = 0; j < 4; j++) {
                    float4 v = ap[j];
                    tmp[4*j+0] = f2b(v.x); tmp[4*j+1] = f2b(v.y);
                    tmp[4*j+2] = f2b(v.z); tmp[4*j+3] = f2b(v.w);
                }
            } else {
                #pragma unroll
                for (int j = 0; j < 16; j++) {
                    int kk = k0 + scol + j;
                    tmp[j] = (ar < N && kk < K) ? f2b(A[(size_t)ar * K + kk])
                                                : (unsigned short)0;
                }
            }
            *(u16x8*)&As[srow][scol]     = *(u16x8*)&tmp[0];
            *(u16x8*)&As[srow][scol + 8] = *(u16x8*)&tmp[8];
        }
        {
            int wr = col0 + srow;
            if (wr < M && k0 + 64 <= K) {
                const u16x8* wp = (const u16x8*)(W + (size_t)wr * K + k0 + scol);
                *(u16x8*)&Bs[srow][scol]     = wp[0];
                *(u16x8*)&Bs[srow][scol + 8] = wp[1];
            } else {
                unsigned short tmp[16];
                #pragma unroll
                for (int j = 0; j < 16; j++) {
                    int kk = k0 + scol + j;
                    tmp[j] = (wr < M && kk < K) ? W[(size_t)wr * K + kk]
                                                : (unsigned short)0;
                }
                *(u16x8*)&Bs[srow][scol]     = *(u16x8*)&tmp[0];
                *(u16x8*)&Bs[srow][scol + 8] = *(u16x8*)&tmp[8];
            }
        }
        __syncthreads();
        #pragma unroll
        for (int kt = 0; kt < 64; kt += 32) {
            bf16x8 af = *(bf16x8*)&As[(wave << 4) + l16][kt + (quad << 3)];
            #pragma unroll
            for (int n0 = 0; n0 < 4; n0++) {
                bf16x8 bf = *(bf16x8*)&Bs[(n0 << 4) + l16][kt + (quad << 3)];
                acc[n0] = __builtin_amdgcn_mfma_f32_16x16x32_bf16(af, bf, acc[n0], 0, 0, 0);
            }
        }
        __syncthreads();
    }
    #pragma unroll
    for (int n0 = 0; n0 < 4; n0++) {
        int col = col0 + (n0 << 4) + l16;
        if (col >= M) continue;
        float bv = bias ? bias[col] : 0.f;
        #pragma unroll
        for (int r = 0; r < 4; r++) {
            int row = row0 + (wave << 4) + (quad << 2) + r;
            if (row >= N) continue;
            float v = acc[n0][r] + bv;
            if (res) v += res[(size_t)row * M + col];
            if (relu) v = fmaxf(v, 0.f);
            C[(size_t)row * M + col] = v;
        }
    }
}

// ---------------------------------------------------------------------------
// Fused QKV GEMM: A[2047,256] x [Wq;Wk;Wv] -> bf16 attention layouts:
//   qbh [h][q][d]  (x 0.25506362 = 1/sqrt(32)*log2(e), exp2-domain logits)
//   kbh [h][t][d]  (+ bk bias)
//   vbT [h][d][t]  (transposed for O^T = V^T P^T MFMA)
// ---------------------------------------------------------------------------
__global__ __launch_bounds__(256, 2) void gemm_qkv(
    const float* __restrict__ A, const unsigned short* __restrict__ Wq,
    const unsigned short* __restrict__ Wk, const unsigned short* __restrict__ Wv,
    const float* __restrict__ bk,
    unsigned short* __restrict__ qbh, unsigned short* __restrict__ kbh,
    unsigned short* __restrict__ vbT)
{
    __shared__ unsigned short As[64][LDK];
    __shared__ unsigned short Bs[64][LDK];
    const int N = S_ROWS, K = 256;
    int tid = threadIdx.x;
    int wave = tid >> 6, lane = tid & 63;
    int quad = lane >> 4, l16 = lane & 15;
    int row0 = blockIdx.y << 6, col0 = blockIdx.x << 6;
    int mode = col0 >> 8;                 // 0=q 1=k 2=v
    int wcol0 = col0 & 255;
    const unsigned short* W = (mode == 0) ? Wq : (mode == 1) ? Wk : Wv;
    int srow = tid >> 2, scol = (tid & 3) << 4;

    f32x4 acc[4];
    #pragma unroll
    for (int i = 0; i < 4; i++) { f32x4 z = {0.f,0.f,0.f,0.f}; acc[i] = z; }

    for (int k0 = 0; k0 < K; k0 += 64) {
        {
            int ar = row0 + srow;
            unsigned short tmp[16];
            if (ar < N) {
                const float4* ap = (const float4*)(A + (size_t)ar * K + k0 + scol);
                #pragma unroll
                for (int j = 0; j < 4; j++) {
                    float4 v = ap[j];
                    tmp[4*j+0] = f2b(v.x); tmp[4*j+1] = f2b(v.y);
                    tmp[4*j+2] = f2b(v.z); tmp[4*j+3] = f2b(v.w);
                }
            } else {
                #pragma unroll
                for (int j = 0; j < 16; j++) tmp[j] = 0;
            }
            *(u16x8*)&As[srow][scol]     = *(u16x8*)&tmp[0];
            *(u16x8*)&As[srow][scol + 8] = *(u16x8*)&tmp[8];
        }
        {
            const u16x8* wp = (const u16x8*)(W + (size_t)(wcol0 + srow) * K + k0 + scol);
            *(u16x8*)&Bs[srow][scol]     = wp[0];
            *(u16x8*)&Bs[srow][scol + 8] = wp[1];
        }
        __syncthreads();
        #pragma unroll
        for (int kt = 0; kt < 64; kt += 32) {
            bf16x8 af = *(bf16x8*)&As[(wave << 4) + l16][kt + (quad << 3)];
            #pragma unroll
            for (int n0 = 0; n0 < 4; n0++) {
                bf16x8 bf = *(bf16x8*)&Bs[(n0 << 4) + l16][kt + (quad << 3)];
                acc[n0] = __builtin_amdgcn_mfma_f32_16x16x32_bf16(af, bf, acc[n0], 0, 0, 0);
            }
        }
        __syncthreads();
    }
    #pragma unroll
    for (int n0 = 0; n0 < 4; n0++) {
        int colr = wcol0 + (n0 << 4) + l16;      // 0..255
        int hh = colr >> 5, d = colr & 31;
        int rbase = row0 + (wave << 4) + (quad << 2);
        if (mode == 2) {
            unsigned short* dst = vbT + ((size_t)hh * 32 + d) * 2048 + rbase;
            if (rbase + 3 < N) {
                u16x4 o;
                #pragma unroll
                for (int r = 0; r < 4; r++) o[r] = f2b(acc[n0][r]);
                *(u16x4*)dst = o;
            } else {
                #pragma unroll
                for (int r = 0; r < 4; r++)
                    if (rbase + r < N) dst[r] = f2b(acc[n0][r]);
            }
        } else {
            float bias = (mode == 1) ? bk[colr] : 0.f;
            unsigned short* dst = ((mode == 0) ? qbh : kbh) + (size_t)hh * 2048 * 32 + d;
            #pragma unroll
            for (int r = 0; r < 4; r++) {
                int row = rbase + r;
                if (row < N) {
                    float v = acc[n0][r] + bias;
                    if (mode == 0) v *= 0.25506362f;
                    dst[(size_t)row * 32] = f2b(v);
                }
            }
        }
    }
}

// ---------------------------------------------------------------------------
// MFMA flash attention. 1 wave = 32 queries x 1 head; 32-key steps.
// S^T = K.Q^T (2x mfma 32x32x16), softmax in exp2-domain (Q pre-scaled),
// O^T = V^T.P^T (2x mfma). P^T B-frags via half-wave shfl_xor(32).
// grid (64 qtiles, 8 heads, KCHUNKS), 64 threads.
// ---------------------------------------------------------------------------
__global__ __launch_bounds__(64) void attn_mfma(
    const unsigned short* __restrict__ qbh,
    const unsigned short* __restrict__ kbh,
    const unsigned short* __restrict__ vbT,
    float* __restrict__ part_o, float* __restrict__ part_ml)
{
    int lane = threadIdx.x;
    int l31 = lane & 31, hf = lane >> 5;
    int q0 = blockIdx.x << 5;
    int h = blockIdx.y, c = blockIdx.z;
    int kstart = c * 512;
    int kend = min(kstart + 512, S_ROWS);

    const unsigned short* qp = qbh + ((size_t)h * 2048 + (q0 + l31)) * 32 + hf * 8;
    bf16x8 qf0 = *(const bf16x8*)(qp);
    bf16x8 qf1 = *(const bf16x8*)(qp + 16);

    const unsigned short* kb_h = kbh + (size_t)h * 2048 * 32;
    const unsigned short* vb_h = vbT + ((size_t)h * 32 + l31) * 2048;

    f32x16 acc = {};
    float m = -1e30f, l = 0.f;

    for (int key0 = kstart; key0 < kend; key0 += 32) {
        const unsigned short* kp = kb_h + (size_t)(key0 + l31) * 32 + hf * 8;
        bf16x8 kf0 = *(const bf16x8*)(kp);
        bf16x8 kf1 = *(const bf16x8*)(kp + 16);
        bf16x8 vf0 = *(const bf16x8*)(vb_h + key0 + hf * 8);
        bf16x8 vf1 = *(const bf16x8*)(vb_h + key0 + 16 + hf * 8);

        f32x16 sc = {};
        sc = __builtin_amdgcn_mfma_f32_32x32x16_bf16(kf0, qf0, sc, 0, 0, 0);
        sc = __builtin_amdgcn_mfma_f32_32x32x16_bf16(kf1, qf1, sc, 0, 0, 0);

        if (key0 + 32 > kend) {
            #pragma unroll
            for (int r = 0; r < 16; r++) {
                int kr = key0 + (r & 3) + 8 * (r >> 2) + 4 * hf;
                if (kr >= kend) sc[r] = -1e30f;
            }
        }
        float tmax = sc[0];
        #pragma unroll
        for (int r = 1; r < 16; r++) tmax = fmaxf(tmax, sc[r]);
        tmax = fmaxf(tmax, __shfl_xor(tmax, 32, 64));
        float mnew = fmaxf(m, tmax);
        float corr = __builtin_amdgcn_exp2f(m - mnew);
        m = mnew;
        float p[16];
        float ls = 0.f;
        #pragma unroll
        for (int r = 0; r < 16; r++) {
            p[r] = __builtin_amdgcn_exp2f(sc[r] - mnew);
            ls += p[r];
        }
        ls += __shfl_xor(ls, 32, 64);
        l = l * corr + ls;
        if (__ballot(corr != 1.0f)) {
            #pragma unroll
            for (int r = 0; r < 16; r++) acc[r] *= corr;
        }
        // pack P to bf16 (truncate via v_perm): pk[i] = keys (2i,2i+1) of own set
        unsigned int pk[8];
        #pragma unroll
        for (int i = 0; i < 8; i++)
            pk[i] = __builtin_amdgcn_perm(__float_as_uint(p[2*i+1]),
                                          __float_as_uint(p[2*i]), 0x07060302u);
        unsigned int x[8];
        #pragma unroll
        for (int i = 0; i < 8; i++)
            x[i] = (unsigned int)__shfl_xor((int)pk[i], 32, 64);
        union { unsigned int u[4]; bf16x8 v; } B1, B2;
        B1.u[0] = hf ? x[2]  : pk[0];
        B1.u[1] = hf ? x[3]  : pk[1];
        B1.u[2] = hf ? pk[2] : x[0];
        B1.u[3] = hf ? pk[3] : x[1];
        B2.u[0] = hf ? x[6]  : pk[4];
        B2.u[1] = hf ? x[7]  : pk[5];
        B2.u[2] = hf ? pk[6] : x[4];
        B2.u[3] = hf ? pk[7] : x[5];
        acc = __builtin_amdgcn_mfma_f32_32x32x16_bf16(vf0, B1.v, acc, 0, 0, 0);
        acc = __builtin_amdgcn_mfma_f32_32x32x16_bf16(vf1, B2.v, acc, 0, 0, 0);
    }

    int q = q0 + l31;
    size_t ob_base = ((size_t)(c * NHEADS + h) * 2048 + q) * 32;
    #pragma unroll
    for (int g = 0; g < 4; g++) {
        float4 o4;
        o4.x = acc[4*g]; o4.y = acc[4*g+1]; o4.z = acc[4*g+2]; o4.w = acc[4*g+3];
        *(float4*)(part_o + ob_base + 4*hf + 8*g) = o4;
    }
    if (!hf) {
        size_t mlb = ((size_t)(c * NHEADS + h) * 2048 + q) * 2;
        part_ml[mlb] = m; part_ml[mlb + 1] = l;
    }
}

__global__ __launch_bounds__(256) void attn_combine(
    const float* __restrict__ part_o, const float* __restrict__ part_ml,
    float* __restrict__ ob)
{
    int idx = blockIdx.x * 256 + threadIdx.x;
    if (idx >= S_ROWS * NHEADS) return;
    int h = idx & 7, q = idx >> 3;
    float m = -1e30f;
    #pragma unroll
    for (int c = 0; c < KCHUNKS; c++)
        m = fmaxf(m, part_ml[((size_t)(c * NHEADS + h) * 2048 + q) * 2]);
    float l = 0.f;
    float num[32];
    #pragma unroll
    for (int d = 0; d < 32; d++) num[d] = 0.f;
    #pragma unroll
    for (int c = 0; c < KCHUNKS; c++) {
        size_t rec = (size_t)(c * NHEADS + h) * 2048 + q;
        float2 mlv = *(const float2*)(part_ml + rec * 2);
        float w = __builtin_amdgcn_exp2f(mlv.x - m);
        l += mlv.y * w;
        const float* po = part_o + rec * 32;
        #pragma unroll
        for (int d4 = 0; d4 < 8; d4++) {
            float4 o4 = *(const float4*)(po + 4 * d4);
            num[4*d4+0] = fmaf(o4.x, w, num[4*d4+0]);
            num[4*d4+1] = fmaf(o4.y, w, num[4*d4+1]);
            num[4*d4+2] = fmaf(o4.z, w, num[4*d4+2]);
            num[4*d4+3] = fmaf(o4.w, w, num[4*d4+3]);
        }
    }
    float inv = 1.f / l;
    float* op = ob + (size_t)q * DIM + h * DH;
    #pragma unroll
    for (int d4 = 0; d4 < 8; d4++) {
        float4 o4;
        o4.x = num[4*d4+0]*inv; o4.y = num[4*d4+1]*inv;
        o4.z = num[4*d4+2]*inv; o4.w = num[4*d4+3]*inv;
        *(float4*)(op + 4*d4) = o4;
    }
}

// ---------------------------------------------------------------------------
__global__ void embed_kernel(const float* __restrict__ pos,
    const float* __restrict__ scale, const float* __restrict__ press,
    const float* __restrict__ temp, float* __restrict__ cond)
{
    int i = blockIdx.x * blockDim.x + threadIdx.x;
    if (i >= S_ROWS * 35) return;
    int row = i / 35, c = i % 35;
    float v;
    if (c < 32) {
        int coord = c >> 4;
        int w = c & 15;
        float x = pos[(row + 1) * 3 + coord];
        float f = 6.283185307179586f * (float)((w & 7) + 1);
        float ang = x * f;
        v = (w < 8) ? cosf(ang) : sinf(ang);
    } else if (c == 32) v = scale[0];
    else if (c == 33) v = temp[0];
    else v = press[0];
    cond[(size_t)row * 35 + c] = v;
}

__global__ void copy_pos(const float* __restrict__ pos, float* __restrict__ out)
{
    int i = blockIdx.x * blockDim.x + threadIdx.x;
    if (i < 6144) out[i] = pos[i];
}

// ---------------------------------------------------------------------------
__global__ void spline_kernel(const float* __restrict__ pos,
    const float* __restrict__ params, float* __restrict__ out,
    float* __restrict__ ldp)
{
    int r = blockIdx.x * blockDim.x + threadIdx.x;
    if (r >= S_ROWS) return;
    const float* p = params + (size_t)r * AFF_OUT;
    float x = pos[(r + 1) * 3 + 2];

    float uw[NBINS], uh[NBINS];
    float mw = -1e30f, mh = -1e30f;
    #pragma unroll
    for (int j = 0; j < NBINS; j++) {
        uw[j] = p[j];         mw = fmaxf(mw, uw[j]);
        uh[j] = p[NBINS + j]; mh = fmaxf(mh, uh[j]);
    }
    float sw = 0.f, sh = 0.f;
    #pragma unroll
    for (int j = 0; j < NBINS; j++) {
        uw[j] = __expf(uw[j] - mw); sw += uw[j];
        uh[j] = __expf(uh[j] - mh); sh += uh[j];
    }
    const float span = 1.0f - NBINS * 1e-4f;
    float scw = span / sw, sch = span / sh;

    float xpos[NBINS + 1], ypos[NBINS + 1];
    xpos[0] = 0.f; ypos[0] = 0.f;
    #pragma unroll
    for (int j = 0; j < NBINS; j++) {
        xpos[j + 1] = xpos[j] + (uw[j] * scw + 1e-4f);
        ypos[j + 1] = ypos[j] + (uh[j] * sch + 1e-4f);
    }
    float offset = logf(expm1f(0.9999f));
    float slopes[NBINS + 1];
    #pragma unroll
    for (int j = 0; j <= NBINS; j++) {
        float raw = (j < NBINS) ? p[2 * NBINS + j] : p[2 * NBINS];
        float t = raw + offset;
        slopes[j] = ((t > 15.f) ? t : log1pf(__expf(t))) + 1e-4f;
    }
    float xc = fminf(fmaxf(x, 0.f), 1.f);
    int k = 0;
    #pragma unroll
    for (int j = 1; j < NBINS; j++) if (xc >= xpos[j]) k = j;
    float xk = xpos[k], xk1 = xpos[k + 1];
    float yk = ypos[k], yk1 = ypos[k + 1];
    float dk = slopes[k], dk1 = slopes[k + 1];
    float w = xk1 - xk, hh = yk1 - yk;
    float sl = hh / w;
    float z = (xc - xk) / w;
    float z1 = 1.f - z;
    float den = sl + (dk1 + dk - 2.f * sl) * z * z1;
    float y = yk + hh * (sl * z * z + dk * z * z1) / den;
    float ld = 2.f * logf(sl) + logf(dk1 * z * z + 2.f * sl * z * z1 + dk * z1 * z1)
               - 2.f * logf(den);
    bool inside = (x >= 0.f) && (x <= 1.f);
    y = inside ? y : x;
    ld = inside ? ld : 0.f;
    out[(r + 1) * 3 + 2] = y;
    ldp[r] = ld;
}

__global__ void reduce_kernel(const float* __restrict__ ldp, float* __restrict__ out)
{
    __shared__ float sh[256];
    int tid = threadIdx.x;
    float s = 0.f;
    for (int i = tid; i < S_ROWS; i += 256) s += ldp[i];
    sh[tid] = s;
    __syncthreads();
    for (int st = 128; st > 0; st >>= 1) {
        if (tid < st) sh[tid] += sh[tid + st];
        __syncthreads();
    }
    if (tid == 0) out[6144] = sh[0];
}

// ---------------------------------------------------------------------------
extern "C" void kernel_launch(void* const* d_in, const int* in_sizes, int n_in,
                              void* d_out, int out_size, void* d_ws, size_t ws_size,
                              hipStream_t stream)
{
    const float* pos   = (const float*)d_in[0];
    const float* scale = (const float*)d_in[1];
    const float* press = (const float*)d_in[2];
    const float* temp  = (const float*)d_in[3];
    const float* e_w0  = (const float*)d_in[4];
    const float* e_b0  = (const float*)d_in[5];
    const float* e_w1  = (const float*)d_in[6];
    const float* e_b1  = (const float*)d_in[7];
    const float* e_w2  = (const float*)d_in[8];
    const float* e_b2  = (const float*)d_in[9];
    const float* Wq    = (const float*)d_in[10];
    const float* Wk    = (const float*)d_in[11];
    const float* bk    = (const float*)d_in[12];
    const float* Wv    = (const float*)d_in[13];
    const float* Wo    = (const float*)d_in[14];
    const float* bo    = (const float*)d_in[15];
    const float* mw0   = (const float*)d_in[16];
    const float* mb0   = (const float*)d_in[17];
    const float* mw1   = (const float*)d_in[18];
    const float* mb1   = (const float*)d_in[19];
    const float* mw2   = (const float*)d_in[20];
    const float* mb2   = (const float*)d_in[21];
    const float* a_w0  = (const float*)d_in[22];
    const float* a_b0  = (const float*)d_in[23];
    const float* a_w1  = (const float*)d_in[24];
    const float* a_b1  = (const float*)d_in[25];
    const float* a_w2  = (const float*)d_in[26];
    const float* a_b2  = (const float*)d_in[27];
    float* out = (float*)d_out;

    enum { OFF_EW0 = 0, OFF_EW1 = 17920, OFF_EW2 = 280064, OFF_WQ = 411136,
           OFF_WK = 673280, OFF_WV = 935424, OFF_WO = 1197568, OFF_MW0 = 1459712,
           OFF_MW1 = 1984000, OFF_MW2 = 3032576, OFF_AW0 = 3556864,
           OFF_AW1 = 3687936, OFF_AW2 = 3950080 };

    float* ws = (float*)d_ws;
    size_t off = 0;
    float* cond = ws + off; off += 2048 * 35;
    float* t1   = ws + off; off += 2048 * 512;
    float* t2   = ws + off; off += 2048 * 512;
    float* hbuf = ws + off; off += 2048 * 256;
    float* ob   = ws + off; off += 2048 * 256;
    float* pr   = ws + off; off += 2048 * 64;
    float* ldp  = ws + off; off += 2048;
    unsigned short* wb  = (unsigned short*)(ws + off); off += W_TOTAL / 2;
    unsigned short* qbh = (unsigned short*)(ws + off); off += NHEADS * 2048 * 32 / 2;
    unsigned short* kbh = (unsigned short*)(ws + off); off += NHEADS * 2048 * 32 / 2;
    unsigned short* vbT = (unsigned short*)(ws + off); off += NHEADS * 2048 * 32 / 2;
    float* part_o  = ws + off; off += (size_t)KCHUNKS * NHEADS * 2048 * 32;
    float* part_ml = ws + off; off += (size_t)KCHUNKS * NHEADS * 2048 * 2;
    (void)ws_size;

    dim3 b256(256);
    hipLaunchKernelGGL(convert_weights, dim3(1024), b256, 0, stream,
                       e_w0, e_w1, e_w2, Wq, Wk, Wv, Wo, mw0, mw1, mw2,
                       a_w0, a_w1, a_w2, wb);
    hipLaunchKernelGGL(embed_kernel, dim3((S_ROWS * 35 + 255) / 256), b256, 0, stream,
                       pos, scale, press, temp, cond);
    hipLaunchKernelGGL(copy_pos, dim3(24), b256, 0, stream, pos, out);

    auto gemm = [&](const float* A, const unsigned short* W, const float* bias,
                    const float* res, float* C, int N, int M, int K, int relu) {
        dim3 grid((M + 63) / 64, (N + 63) / 64);
        hipLaunchKernelGGL(gemm_bf16, grid, dim3(256), 0, stream,
                           A, W, bias, res, C, N, M, K, relu);
    };

    // embedding MLP: 35 -> 512 -> 512 -> 256
    gemm(cond, wb + OFF_EW0, e_b0, nullptr, t1, S_ROWS, 512, 35, 1);
    gemm(t1,   wb + OFF_EW1, e_b1, nullptr, t2, S_ROWS, 512, 512, 1);
    gemm(t2,   wb + OFF_EW2, e_b2, nullptr, hbuf, S_ROWS, 256, 512, 0);

    for (int l = 0; l < 4; l++) {
        hipLaunchKernelGGL(gemm_qkv, dim3(12, 32), b256, 0, stream,
                           hbuf, wb + OFF_WQ + l * 65536, wb + OFF_WK + l * 65536,
                           wb + OFF_WV + l * 65536, bk + l * 256, qbh, kbh, vbT);
        hipLaunchKernelGGL(attn_mfma, dim3(64, NHEADS, KCHUNKS), dim3(64), 0, stream,
                           qbh, kbh, vbT, part_o, part_ml);
        hipLaunchKernelGGL(attn_combine, dim3((S_ROWS * NHEADS + 255) / 256), b256,
                           0, stream, part_o, part_ml, ob);
        gemm(ob, wb + OFF_WO + l * 65536, bo + l * 256, hbuf, hbuf, S_ROWS, 256, 256, 0);
        gemm(hbuf, wb + OFF_MW0 + l * 131072, mb0 + l * 512, nullptr, t1, S_ROWS, 512, 256, 1);
        gemm(t1,   wb + OFF_MW1 + l * 262144, mb1 + l * 512, nullptr, t2, S_ROWS, 512, 512, 1);
        gemm(t2,   wb + OFF_MW2 + l * 131072, mb2 + l * 256, hbuf,    hbuf, S_ROWS, 256, 512, 0);
    }

    // affine-param MLP: 256 -> 512 -> 512 -> 49
    gemm(hbuf, wb + OFF_AW0, a_b0, nullptr, t1, S_ROWS, 512, 256, 1);
    gemm(t1,   wb + OFF_AW1, a_b1, nullptr, t2, S_ROWS, 512, 512, 1);
    gemm(t2,   wb + OFF_AW2, a_b2, nullptr, pr, S_ROWS, AFF_OUT, 512, 0);

    hipLaunchKernelGGL(spline_kernel, dim3((S_ROWS + 255) / 256), b256, 0, stream,
                       pos, pr, out, ldp);
    hipLaunchKernelGGL(reduce_kernel, dim3(1), b256, 0, stream, ldp, out);
}

// Round 4
// 476.334 us; speedup vs baseline: 5.1595x; 1.2231x over previous
//
#include <hip/hip_runtime.h>
#include <math.h>

#define S_ROWS 2047
#define DIM 256
#define HID 512
#define NHEADS 8
#define DH 32
#define NBINS 16
#define AFF_OUT 49
#define KCHUNKS 4

typedef short bf16x8 __attribute__((ext_vector_type(8)));
typedef float f32x4 __attribute__((ext_vector_type(4)));
typedef float f32x16 __attribute__((ext_vector_type(16)));
typedef unsigned short u16x8 __attribute__((ext_vector_type(8)));
typedef unsigned short u16x4 __attribute__((ext_vector_type(4)));

__device__ inline unsigned short f2b(float f) {
    unsigned int u = __float_as_uint(f);
    u += 0x7FFFu + ((u >> 16) & 1u);      // round-to-nearest-even
    return (unsigned short)(u >> 16);
}

// ---------------------------------------------------------------------------
// Weight conversion f32 -> bf16. Layout: [ew0 padded 512x64 | 12 segments].
// ---------------------------------------------------------------------------
#define W_MAIN 3957248
#define EW0P_N 32768
__global__ __launch_bounds__(256) void convert_weights(
    const float* __restrict__ e_w0, const float* __restrict__ p0,
    const float* __restrict__ p1, const float* __restrict__ p2,
    const float* __restrict__ p3, const float* __restrict__ p4,
    const float* __restrict__ p5, const float* __restrict__ p6,
    const float* __restrict__ p7, const float* __restrict__ p8,
    const float* __restrict__ p9, const float* __restrict__ p10,
    const float* __restrict__ p11, unsigned short* __restrict__ dst)
{
    const int offs[13] = {0, 262144, 393216, 655360, 917504, 1179648, 1441792,
                          1966080, 3014656, 3538944, 3670016, 3932160, 3957248};
    const float* srcs[12] = {p0,p1,p2,p3,p4,p5,p6,p7,p8,p9,p10,p11};
    int n4main = W_MAIN / 4;
    int n4tot = n4main + EW0P_N / 4;
    for (int i4 = blockIdx.x * blockDim.x + threadIdx.x; i4 < n4tot;
         i4 += gridDim.x * blockDim.x) {
        if (i4 < n4main) {
            int e = i4 * 4;
            int s = 0;
            #pragma unroll
            for (int j = 1; j < 12; j++) s += (e >= offs[j]);
            const float4 v = *(const float4*)(srcs[s] + (e - offs[s]));
            u16x4 o;
            o[0] = f2b(v.x); o[1] = f2b(v.y); o[2] = f2b(v.z); o[3] = f2b(v.w);
            *(u16x4*)(dst + EW0P_N + e) = o;
        } else {
            int e = (i4 - n4main) * 4;
            u16x4 o;
            #pragma unroll
            for (int r = 0; r < 4; r++) {
                int ee = e + r;
                int row = ee >> 6, col = ee & 63;
                o[r] = (col < 35) ? f2b(e_w0[row * 35 + col]) : (unsigned short)0;
            }
            *(u16x4*)(dst + e) = o;
        }
    }
}

// ---------------------------------------------------------------------------
// bf16 MFMA GEMM: C[2047,M] = act(Ab[2048,K] @ W[M,K]^T + bias + resF)
// Ab bf16 (2048 rows, K mult of 64). Writes f32 Cf and/or bf16 Cb.
// 64x64 tile, 4 waves, mfma_f32_16x16x32_bf16, branch-free staging.
// ---------------------------------------------------------------------------
#define LDK 72
__global__ __launch_bounds__(256, 2) void gemm_bf16(
    const unsigned short* __restrict__ Ab, const unsigned short* __restrict__ W,
    const float* __restrict__ bias, const float* resF,
    float* Cf, unsigned short* Cb, int M, int K, int relu)
{
    __shared__ unsigned short As[64][LDK];
    __shared__ unsigned short Bs[64][LDK];
    int tid = threadIdx.x;
    int wave = tid >> 6, lane = tid & 63;
    int quad = lane >> 4, l16 = lane & 15;
    int row0 = blockIdx.y << 6, col0 = blockIdx.x << 6;
    int srow = tid >> 2, scol = (tid & 3) << 4;

    f32x4 acc[4];
    #pragma unroll
    for (int i = 0; i < 4; i++) { f32x4 z = {0.f,0.f,0.f,0.f}; acc[i] = z; }

    for (int k0 = 0; k0 < K; k0 += 64) {
        const u16x8* ap = (const u16x8*)(Ab + (size_t)(row0 + srow) * K + k0 + scol);
        *(u16x8*)&As[srow][scol]     = ap[0];
        *(u16x8*)&As[srow][scol + 8] = ap[1];
        const u16x8* wp = (const u16x8*)(W + (size_t)(col0 + srow) * K + k0 + scol);
        *(u16x8*)&Bs[srow][scol]     = wp[0];
        *(u16x8*)&Bs[srow][scol + 8] = wp[1];
        __syncthreads();
        #pragma unroll
        for (int kt = 0; kt < 64; kt += 32) {
            bf16x8 af = *(bf16x8*)&As[(wave << 4) + l16][kt + (quad << 3)];
            #pragma unroll
            for (int n0 = 0; n0 < 4; n0++) {
                bf16x8 bf = *(bf16x8*)&Bs[(n0 << 4) + l16][kt + (quad << 3)];
                acc[n0] = __builtin_amdgcn_mfma_f32_16x16x32_bf16(af, bf, acc[n0], 0, 0, 0);
            }
        }
        __syncthreads();
    }
    #pragma unroll
    for (int n0 = 0; n0 < 4; n0++) {
        int col = col0 + (n0 << 4) + l16;
        if (col >= M) continue;
        float bv = bias ? bias[col] : 0.f;
        #pragma unroll
        for (int r = 0; r < 4; r++) {
            int row = row0 + (wave << 4) + (quad << 2) + r;
            if (row >= S_ROWS) continue;
            float v = acc[n0][r] + bv;
            if (resF) v += resF[(size_t)row * M + col];
            if (relu) v = fmaxf(v, 0.f);
            if (Cf) Cf[(size_t)row * M + col] = v;
            if (Cb) Cb[(size_t)row * M + col] = f2b(v);
        }
    }
}

// ---------------------------------------------------------------------------
// Fused QKV GEMM from bf16 activations -> attention-native bf16 layouts:
//   qbh [h][q][d] (x 0.25506362 = 1/sqrt(32)*log2e), kbh [h][t][d] (+bk),
//   vbT [h][d][t].
// ---------------------------------------------------------------------------
__global__ __launch_bounds__(256, 2) void gemm_qkv(
    const unsigned short* __restrict__ Ab, const unsigned short* __restrict__ Wq,
    const unsigned short* __restrict__ Wk, const unsigned short* __restrict__ Wv,
    const float* __restrict__ bk,
    unsigned short* __restrict__ qbh, unsigned short* __restrict__ kbh,
    unsigned short* __restrict__ vbT)
{
    __shared__ unsigned short As[64][LDK];
    __shared__ unsigned short Bs[64][LDK];
    const int N = S_ROWS, K = 256;
    int tid = threadIdx.x;
    int wave = tid >> 6, lane = tid & 63;
    int quad = lane >> 4, l16 = lane & 15;
    int row0 = blockIdx.y << 6, col0 = blockIdx.x << 6;
    int mode = col0 >> 8;                 // 0=q 1=k 2=v
    int wcol0 = col0 & 255;
    const unsigned short* W = (mode == 0) ? Wq : (mode == 1) ? Wk : Wv;
    int srow = tid >> 2, scol = (tid & 3) << 4;

    f32x4 acc[4];
    #pragma unroll
    for (int i = 0; i < 4; i++) { f32x4 z = {0.f,0.f,0.f,0.f}; acc[i] = z; }

    for (int k0 = 0; k0 < K; k0 += 64) {
        const u16x8* ap = (const u16x8*)(Ab + (size_t)(row0 + srow) * K + k0 + scol);
        *(u16x8*)&As[srow][scol]     = ap[0];
        *(u16x8*)&As[srow][scol + 8] = ap[1];
        const u16x8* wp = (const u16x8*)(W + (size_t)(wcol0 + srow) * K + k0 + scol);
        *(u16x8*)&Bs[srow][scol]     = wp[0];
        *(u16x8*)&Bs[srow][scol + 8] = wp[1];
        __syncthreads();
        #pragma unroll
        for (int kt = 0; kt < 64; kt += 32) {
            bf16x8 af = *(bf16x8*)&As[(wave << 4) + l16][kt + (quad << 3)];
            #pragma unroll
            for (int n0 = 0; n0 < 4; n0++) {
                bf16x8 bf = *(bf16x8*)&Bs[(n0 << 4) + l16][kt + (quad << 3)];
                acc[n0] = __builtin_amdgcn_mfma_f32_16x16x32_bf16(af, bf, acc[n0], 0, 0, 0);
            }
        }
        __syncthreads();
    }
    #pragma unroll
    for (int n0 = 0; n0 < 4; n0++) {
        int colr = wcol0 + (n0 << 4) + l16;      // 0..255
        int hh = colr >> 5, d = colr & 31;
        int rbase = row0 + (wave << 4) + (quad << 2);
        if (mode == 2) {
            unsigned short* dst = vbT + ((size_t)hh * 32 + d) * 2048 + rbase;
            if (rbase + 3 < N) {
                u16x4 o;
                #pragma unroll
                for (int r = 0; r < 4; r++) o[r] = f2b(acc[n0][r]);
                *(u16x4*)dst = o;
            } else {
                #pragma unroll
                for (int r = 0; r < 4; r++)
                    if (rbase + r < N) dst[r] = f2b(acc[n0][r]);
            }
        } else {
            float bias = (mode == 1) ? bk[colr] : 0.f;
            unsigned short* dst = ((mode == 0) ? qbh : kbh) + (size_t)hh * 2048 * 32 + d;
            #pragma unroll
            for (int r = 0; r < 4; r++) {
                int row = rbase + r;
                if (row < N) {
                    float v = acc[n0][r] + bias;
                    if (mode == 0) v *= 0.25506362f;
                    dst[(size_t)row * 32] = f2b(v);
                }
            }
        }
    }
}

// ---------------------------------------------------------------------------
// MFMA flash attention (unchanged from R2). 1 wave = 32 queries x 1 head.
// ---------------------------------------------------------------------------
__global__ __launch_bounds__(64) void attn_mfma(
    const unsigned short* __restrict__ qbh,
    const unsigned short* __restrict__ kbh,
    const unsigned short* __restrict__ vbT,
    float* __restrict__ part_o, float* __restrict__ part_ml)
{
    int lane = threadIdx.x;
    int l31 = lane & 31, hf = lane >> 5;
    int q0 = blockIdx.x << 5;
    int h = blockIdx.y, c = blockIdx.z;
    int kstart = c * 512;
    int kend = min(kstart + 512, S_ROWS);

    const unsigned short* qp = qbh + ((size_t)h * 2048 + (q0 + l31)) * 32 + hf * 8;
    bf16x8 qf0 = *(const bf16x8*)(qp);
    bf16x8 qf1 = *(const bf16x8*)(qp + 16);

    const unsigned short* kb_h = kbh + (size_t)h * 2048 * 32;
    const unsigned short* vb_h = vbT + ((size_t)h * 32 + l31) * 2048;

    f32x16 acc = {};
    float m = -1e30f, l = 0.f;

    for (int key0 = kstart; key0 < kend; key0 += 32) {
        const unsigned short* kp = kb_h + (size_t)(key0 + l31) * 32 + hf * 8;
        bf16x8 kf0 = *(const bf16x8*)(kp);
        bf16x8 kf1 = *(const bf16x8*)(kp + 16);
        bf16x8 vf0 = *(const bf16x8*)(vb_h + key0 + hf * 8);
        bf16x8 vf1 = *(const bf16x8*)(vb_h + key0 + 16 + hf * 8);

        f32x16 sc = {};
        sc = __builtin_amdgcn_mfma_f32_32x32x16_bf16(kf0, qf0, sc, 0, 0, 0);
        sc = __builtin_amdgcn_mfma_f32_32x32x16_bf16(kf1, qf1, sc, 0, 0, 0);

        if (key0 + 32 > kend) {
            #pragma unroll
            for (int r = 0; r < 16; r++) {
                int kr = key0 + (r & 3) + 8 * (r >> 2) + 4 * hf;
                if (kr >= kend) sc[r] = -1e30f;
            }
        }
        float tmax = sc[0];
        #pragma unroll
        for (int r = 1; r < 16; r++) tmax = fmaxf(tmax, sc[r]);
        tmax = fmaxf(tmax, __shfl_xor(tmax, 32, 64));
        float mnew = fmaxf(m, tmax);
        float corr = __builtin_amdgcn_exp2f(m - mnew);
        m = mnew;
        float p[16];
        float ls = 0.f;
        #pragma unroll
        for (int r = 0; r < 16; r++) {
            p[r] = __builtin_amdgcn_exp2f(sc[r] - mnew);
            ls += p[r];
        }
        ls += __shfl_xor(ls, 32, 64);
        l = l * corr + ls;
        if (__ballot(corr != 1.0f)) {
            #pragma unroll
            for (int r = 0; r < 16; r++) acc[r] *= corr;
        }
        unsigned int pk[8];
        #pragma unroll
        for (int i = 0; i < 8; i++)
            pk[i] = __builtin_amdgcn_perm(__float_as_uint(p[2*i+1]),
                                          __float_as_uint(p[2*i]), 0x07060302u);
        unsigned int x[8];
        #pragma unroll
        for (int i = 0; i < 8; i++)
            x[i] = (unsigned int)__shfl_xor((int)pk[i], 32, 64);
        union { unsigned int u[4]; bf16x8 v; } B1, B2;
        B1.u[0] = hf ? x[2]  : pk[0];
        B1.u[1] = hf ? x[3]  : pk[1];
        B1.u[2] = hf ? pk[2] : x[0];
        B1.u[3] = hf ? pk[3] : x[1];
        B2.u[0] = hf ? x[6]  : pk[4];
        B2.u[1] = hf ? x[7]  : pk[5];
        B2.u[2] = hf ? pk[6] : x[4];
        B2.u[3] = hf ? pk[7] : x[5];
        acc = __builtin_amdgcn_mfma_f32_32x32x16_bf16(vf0, B1.v, acc, 0, 0, 0);
        acc = __builtin_amdgcn_mfma_f32_32x32x16_bf16(vf1, B2.v, acc, 0, 0, 0);
    }

    int q = q0 + l31;
    size_t ob_base = ((size_t)(c * NHEADS + h) * 2048 + q) * 32;
    #pragma unroll
    for (int g = 0; g < 4; g++) {
        float4 o4;
        o4.x = acc[4*g]; o4.y = acc[4*g+1]; o4.z = acc[4*g+2]; o4.w = acc[4*g+3];
        *(float4*)(part_o + ob_base + 4*hf + 8*g) = o4;
    }
    if (!hf) {
        size_t mlb = ((size_t)(c * NHEADS + h) * 2048 + q) * 2;
        part_ml[mlb] = m; part_ml[mlb + 1] = l;
    }
}

__global__ __launch_bounds__(256) void attn_combine(
    const float* __restrict__ part_o, const float* __restrict__ part_ml,
    unsigned short* __restrict__ obb)
{
    int idx = blockIdx.x * 256 + threadIdx.x;
    if (idx >= S_ROWS * NHEADS) return;
    int h = idx & 7, q = idx >> 3;
    float m = -1e30f;
    #pragma unroll
    for (int c = 0; c < KCHUNKS; c++)
        m = fmaxf(m, part_ml[((size_t)(c * NHEADS + h) * 2048 + q) * 2]);
    float l = 0.f;
    float num[32];
    #pragma unroll
    for (int d = 0; d < 32; d++) num[d] = 0.f;
    #pragma unroll
    for (int c = 0; c < KCHUNKS; c++) {
        size_t rec = (size_t)(c * NHEADS + h) * 2048 + q;
        float2 mlv = *(const float2*)(part_ml + rec * 2);
        float w = __builtin_amdgcn_exp2f(mlv.x - m);
        l += mlv.y * w;
        const float* po = part_o + rec * 32;
        #pragma unroll
        for (int d4 = 0; d4 < 8; d4++) {
            float4 o4 = *(const float4*)(po + 4 * d4);
            num[4*d4+0] = fmaf(o4.x, w, num[4*d4+0]);
            num[4*d4+1] = fmaf(o4.y, w, num[4*d4+1]);
            num[4*d4+2] = fmaf(o4.z, w, num[4*d4+2]);
            num[4*d4+3] = fmaf(o4.w, w, num[4*d4+3]);
        }
    }
    float inv = 1.f / l;
    unsigned short* op = obb + (size_t)q * DIM + h * DH;
    #pragma unroll
    for (int g = 0; g < 4; g++) {
        u16x8 o8;
        #pragma unroll
        for (int j = 0; j < 8; j++) o8[j] = f2b(num[8*g + j] * inv);
        *(u16x8*)(op + 8*g) = o8;
    }
}

// ---------------------------------------------------------------------------
// cond features in bf16, padded to 64 cols (cols 35..63 = 0, row 2047 = 0)
// ---------------------------------------------------------------------------
__global__ void embed_kernel(const float* __restrict__ pos,
    const float* __restrict__ scale, const float* __restrict__ press,
    const float* __restrict__ temp, unsigned short* __restrict__ cond)
{
    int i = blockIdx.x * blockDim.x + threadIdx.x;
    if (i >= 2048 * 64) return;
    int row = i >> 6, c = i & 63;
    float v = 0.f;
    if (row < S_ROWS) {
        if (c < 32) {
            int coord = c >> 4;
            int w = c & 15;
            float x = pos[(row + 1) * 3 + coord];
            float f = 6.283185307179586f * (float)((w & 7) + 1);
            float ang = x * f;
            v = (w < 8) ? cosf(ang) : sinf(ang);
        } else if (c == 32) v = scale[0];
        else if (c == 33) v = temp[0];
        else if (c == 34) v = press[0];
    }
    cond[i] = f2b(v);
}

__global__ void copy_pos(const float* __restrict__ pos, float* __restrict__ out)
{
    int i = blockIdx.x * blockDim.x + threadIdx.x;
    if (i < 6144) out[i] = pos[i];
    else if (i == 6144) out[6144] = 0.f;
}

// ---------------------------------------------------------------------------
// RQS spline, register-only (no dynamically-indexed arrays -> no scratch),
// fused logdet block-reduction + atomicAdd into out[6144].
// ---------------------------------------------------------------------------
__global__ __launch_bounds__(256) void spline_kernel(const float* __restrict__ pos,
    const float* __restrict__ params, float* __restrict__ out)
{
    int r = blockIdx.x * 256 + threadIdx.x;
    float ld = 0.f;
    if (r < S_ROWS) {
        const float* p = params + (size_t)r * AFF_OUT;
        float x = pos[(r + 1) * 3 + 2];
        float xc = fminf(fmaxf(x, 0.f), 1.f);

        float mw = -1e30f, mh = -1e30f;
        #pragma unroll
        for (int j = 0; j < NBINS; j++) {
            mw = fmaxf(mw, p[j]);
            mh = fmaxf(mh, p[NBINS + j]);
        }
        float sw = 0.f, sh = 0.f;
        #pragma unroll
        for (int j = 0; j < NBINS; j++) {
            sw += __expf(p[j] - mw);
            sh += __expf(p[NBINS + j] - mh);
        }
        const float span = 1.0f - NBINS * 1e-4f;
        float scw = span / sw, sch = span / sh;

        float cumw = 0.f, cumh = 0.f;
        float xk = 0.f, yk = 0.f, wk = 0.f, hk = 0.f;
        int k = 0;
        #pragma unroll
        for (int j = 0; j < NBINS; j++) {
            float wj = __expf(p[j] - mw) * scw + 1e-4f;
            float hj = __expf(p[NBINS + j] - mh) * sch + 1e-4f;
            if (xc >= cumw) { k = j; xk = cumw; yk = cumh; wk = wj; hk = hj; }
            cumw += wj; cumh += hj;
        }
        float offset = logf(expm1f(0.9999f));
        float t0 = p[2 * NBINS + k] + offset;
        float t1 = ((k == NBINS - 1) ? p[2 * NBINS] : p[2 * NBINS + k + 1]) + offset;
        float dk  = ((t0 > 15.f) ? t0 : log1pf(__expf(t0))) + 1e-4f;
        float dk1 = ((t1 > 15.f) ? t1 : log1pf(__expf(t1))) + 1e-4f;

        float sl = hk / wk;
        float z = (xc - xk) / wk;
        float z1 = 1.f - z;
        float den = sl + (dk1 + dk - 2.f * sl) * z * z1;
        float y = yk + hk * (sl * z * z + dk * z * z1) / den;
        float ldv = 2.f * logf(sl)
                  + logf(dk1 * z * z + 2.f * sl * z * z1 + dk * z1 * z1)
                  - 2.f * logf(den);
        bool inside = (x >= 0.f) && (x <= 1.f);
        y = inside ? y : x;
        ld = inside ? ldv : 0.f;
        out[(r + 1) * 3 + 2] = y;
    }
    __shared__ float sh[256];
    int tid = threadIdx.x;
    sh[tid] = ld;
    __syncthreads();
    for (int st = 128; st > 0; st >>= 1) {
        if (tid < st) sh[tid] += sh[tid + st];
        __syncthreads();
    }
    if (tid == 0) atomicAdd(&out[6144], sh[0]);
}

// ---------------------------------------------------------------------------
extern "C" void kernel_launch(void* const* d_in, const int* in_sizes, int n_in,
                              void* d_out, int out_size, void* d_ws, size_t ws_size,
                              hipStream_t stream)
{
    const float* pos   = (const float*)d_in[0];
    const float* scale = (const float*)d_in[1];
    const float* press = (const float*)d_in[2];
    const float* temp  = (const float*)d_in[3];
    const float* e_w0  = (const float*)d_in[4];
    const float* e_b0  = (const float*)d_in[5];
    const float* e_w1  = (const float*)d_in[6];
    const float* e_b1  = (const float*)d_in[7];
    const float* e_w2  = (const float*)d_in[8];
    const float* e_b2  = (const float*)d_in[9];
    const float* Wq    = (const float*)d_in[10];
    const float* Wk    = (const float*)d_in[11];
    const float* bk    = (const float*)d_in[12];
    const float* Wv    = (const float*)d_in[13];
    const float* Wo    = (const float*)d_in[14];
    const float* bo    = (const float*)d_in[15];
    const float* mw0   = (const float*)d_in[16];
    const float* mb0   = (const float*)d_in[17];
    const float* mw1   = (const float*)d_in[18];
    const float* mb1   = (const float*)d_in[19];
    const float* mw2   = (const float*)d_in[20];
    const float* mb2   = (const float*)d_in[21];
    const float* a_w0  = (const float*)d_in[22];
    const float* a_b0  = (const float*)d_in[23];
    const float* a_w1  = (const float*)d_in[24];
    const float* a_b1  = (const float*)d_in[25];
    const float* a_w2  = (const float*)d_in[26];
    const float* a_b2  = (const float*)d_in[27];
    float* out = (float*)d_out;

    // bf16 weight region offsets (u16 elements): [ew0p | main segments]
    enum { OFF_EW0 = 0,
           OFF_EW1 = 32768 + 0,       OFF_EW2 = 32768 + 262144,
           OFF_WQ  = 32768 + 393216,  OFF_WK  = 32768 + 655360,
           OFF_WV  = 32768 + 917504,  OFF_WO  = 32768 + 1179648,
           OFF_MW0 = 32768 + 1441792, OFF_MW1 = 32768 + 1966080,
           OFF_MW2 = 32768 + 3014656, OFF_AW0 = 32768 + 3538944,
           OFF_AW1 = 32768 + 3670016, OFF_AW2 = 32768 + 3932160 };
    const size_t WB_U16 = (size_t)EW0P_N + W_MAIN;   // 3990016

    float* ws = (float*)d_ws;
    size_t off = 0;
    float* hbuf = ws + off; off += 2048 * 256;             // f32 residual stream
    float* pr   = ws + off; off += 2048 * 64;              // spline params f32
    unsigned short* wbp   = (unsigned short*)(ws + off); off += WB_U16 / 2;
    unsigned short* cond  = (unsigned short*)(ws + off); off += 2048 * 64 / 2;
    unsigned short* t1b   = (unsigned short*)(ws + off); off += 2048 * 512 / 2;
    unsigned short* t2b   = (unsigned short*)(ws + off); off += 2048 * 512 / 2;
    unsigned short* hb    = (unsigned short*)(ws + off); off += 2048 * 256 / 2;
    unsigned short* obb   = (unsigned short*)(ws + off); off += 2048 * 256 / 2;
    unsigned short* qbh   = (unsigned short*)(ws + off); off += NHEADS * 2048 * 32 / 2;
    unsigned short* kbh   = (unsigned short*)(ws + off); off += NHEADS * 2048 * 32 / 2;
    unsigned short* vbT   = (unsigned short*)(ws + off); off += NHEADS * 2048 * 32 / 2;
    float* part_o  = ws + off; off += (size_t)KCHUNKS * NHEADS * 2048 * 32;
    float* part_ml = ws + off; off += (size_t)KCHUNKS * NHEADS * 2048 * 2;
    (void)ws_size;

    dim3 b256(256);
    hipLaunchKernelGGL(convert_weights, dim3(1024), b256, 0, stream,
                       e_w0, e_w1, e_w2, Wq, Wk, Wv, Wo, mw0, mw1, mw2,
                       a_w0, a_w1, a_w2, wbp);
    hipLaunchKernelGGL(embed_kernel, dim3(512), b256, 0, stream,
                       pos, scale, press, temp, cond);
    hipLaunchKernelGGL(copy_pos, dim3(25), b256, 0, stream, pos, out);

    auto gemm = [&](const unsigned short* A, const unsigned short* W,
                    const float* bias, const float* resF, float* Cf,
                    unsigned short* Cb, int M, int K, int relu) {
        dim3 grid((M + 63) / 64, 32);
        hipLaunchKernelGGL(gemm_bf16, grid, dim3(256), 0, stream,
                           A, W, bias, resF, Cf, Cb, M, K, relu);
    };

    // embedding MLP: 35(->64) -> 512 -> 512 -> 256
    gemm(cond, wbp + OFF_EW0, e_b0, nullptr, nullptr, t1b, 512, 64, 1);
    gemm(t1b,  wbp + OFF_EW1, e_b1, nullptr, nullptr, t2b, 512, 512, 1);
    gemm(t2b,  wbp + OFF_EW2, e_b2, nullptr, hbuf, hb, 256, 512, 0);

    for (int l = 0; l < 4; l++) {
        hipLaunchKernelGGL(gemm_qkv, dim3(12, 32), b256, 0, stream,
                           hb, wbp + OFF_WQ + l * 65536, wbp + OFF_WK + l * 65536,
                           wbp + OFF_WV + l * 65536, bk + l * 256, qbh, kbh, vbT);
        hipLaunchKernelGGL(attn_mfma, dim3(64, NHEADS, KCHUNKS), dim3(64), 0, stream,
                           qbh, kbh, vbT, part_o, part_ml);
        hipLaunchKernelGGL(attn_combine, dim3((S_ROWS * NHEADS + 255) / 256), b256,
                           0, stream, part_o, part_ml, obb);
        gemm(obb, wbp + OFF_WO + l * 65536, bo + l * 256, hbuf, hbuf, hb, 256, 256, 0);
        gemm(hb,  wbp + OFF_MW0 + l * 131072, mb0 + l * 512, nullptr, nullptr, t1b, 512, 256, 1);
        gemm(t1b, wbp + OFF_MW1 + l * 262144, mb1 + l * 512, nullptr, nullptr, t2b, 512, 512, 1);
        gemm(t2b, wbp + OFF_MW2 + l * 131072, mb2 + l * 256, hbuf, hbuf, hb, 256, 512, 0);
    }

    // affine-param MLP: 256 -> 512 -> 512 -> 49
    gemm(hb,  wbp + OFF_AW0, a_b0, nullptr, nullptr, t1b, 512, 256, 1);
    gemm(t1b, wbp + OFF_AW1, a_b1, nullptr, nullptr, t2b, 512, 512, 1);
    gemm(t2b, wbp + OFF_AW2, a_b2, nullptr, pr, nullptr, AFF_OUT, 512, 0);

    hipLaunchKernelGGL(spline_kernel, dim3(8), b256, 0, stream, pos, pr, out);
}

// Round 5
// 459.681 us; speedup vs baseline: 5.3465x; 1.0362x over previous
//
#include <hip/hip_runtime.h>
#include <math.h>

#define S_ROWS 2047
#define DIM 256
#define HID 512
#define NHEADS 8
#define DH 32
#define NBINS 16
#define AFF_OUT 49
#define KCHUNKS 4

typedef short bf16x8 __attribute__((ext_vector_type(8)));
typedef float f32x4 __attribute__((ext_vector_type(4)));
typedef float f32x16 __attribute__((ext_vector_type(16)));
typedef unsigned short u16x8 __attribute__((ext_vector_type(8)));
typedef unsigned short u16x4 __attribute__((ext_vector_type(4)));

__device__ inline unsigned short f2b(float f) {
    unsigned int u = __float_as_uint(f);
    u += 0x7FFFu + ((u >> 16) & 1u);      // round-to-nearest-even
    return (unsigned short)(u >> 16);
}

// ---------------------------------------------------------------------------
// Fused setup: weight f32->bf16 conversion (+ew0 zero-pad to K=64),
// circular-feature embedding (bf16, 64-col padded), pos copy + out[6144]=0.
// One grid-stride kernel, phases by flat i4 index.
// ---------------------------------------------------------------------------
#define W_MAIN 3957248
#define EW0P_N 32768
#define P0 (W_MAIN / 4)                   // main weights (4 elems per i4)
#define P1 (P0 + EW0P_N / 4)              // ew0 padded
#define P2 (P1 + 2048 * 64 / 4)           // cond features
#define P3 (P2 + 1537)                    // pos copy (6148/4)
__global__ __launch_bounds__(256) void setup_kernel(
    const float* __restrict__ pos, const float* __restrict__ scale,
    const float* __restrict__ press, const float* __restrict__ temp,
    const float* __restrict__ e_w0, const float* __restrict__ p0,
    const float* __restrict__ p1, const float* __restrict__ p2,
    const float* __restrict__ p3, const float* __restrict__ p4,
    const float* __restrict__ p5, const float* __restrict__ p6,
    const float* __restrict__ p7, const float* __restrict__ p8,
    const float* __restrict__ p9, const float* __restrict__ p10,
    const float* __restrict__ p11, unsigned short* __restrict__ dst,
    unsigned short* __restrict__ cond, float* __restrict__ out)
{
    const int offs[13] = {0, 262144, 393216, 655360, 917504, 1179648, 1441792,
                          1966080, 3014656, 3538944, 3670016, 3932160, 3957248};
    const float* srcs[12] = {p0,p1,p2,p3,p4,p5,p6,p7,p8,p9,p10,p11};
    for (int i4 = blockIdx.x * blockDim.x + threadIdx.x; i4 < P3;
         i4 += gridDim.x * blockDim.x) {
        if (i4 < P0) {
            int e = i4 * 4;
            int s = 0;
            #pragma unroll
            for (int j = 1; j < 12; j++) s += (e >= offs[j]);
            const float4 v = *(const float4*)(srcs[s] + (e - offs[s]));
            u16x4 o;
            o[0] = f2b(v.x); o[1] = f2b(v.y); o[2] = f2b(v.z); o[3] = f2b(v.w);
            *(u16x4*)(dst + EW0P_N + e) = o;
        } else if (i4 < P1) {
            int e = (i4 - P0) * 4;
            u16x4 o;
            #pragma unroll
            for (int r = 0; r < 4; r++) {
                int ee = e + r;
                int row = ee >> 6, col = ee & 63;
                o[r] = (col < 35) ? f2b(e_w0[row * 35 + col]) : (unsigned short)0;
            }
            *(u16x4*)(dst + e) = o;
        } else if (i4 < P2) {
            int e = (i4 - P1) * 4;
            int row = e >> 6;
            u16x4 o;
            #pragma unroll
            for (int r = 0; r < 4; r++) {
                int c = (e + r) & 63;
                float v = 0.f;
                if (row < S_ROWS) {
                    if (c < 32) {
                        int coord = c >> 4;
                        int w = c & 15;
                        float x = pos[(row + 1) * 3 + coord];
                        float f = 6.283185307179586f * (float)((w & 7) + 1);
                        float ang = x * f;
                        v = (w < 8) ? cosf(ang) : sinf(ang);
                    } else if (c == 32) v = scale[0];
                    else if (c == 33) v = temp[0];
                    else if (c == 34) v = press[0];
                }
                o[r] = f2b(v);
            }
            *(u16x4*)(cond + e) = o;
        } else {
            int e = (i4 - P2) * 4;
            #pragma unroll
            for (int r = 0; r < 4; r++) {
                int ee = e + r;
                if (ee < 6144) out[ee] = pos[ee];
                else if (ee == 6144) out[ee] = 0.f;
            }
        }
    }
}

// ---------------------------------------------------------------------------
// bf16 MFMA GEMM with register-prefetch pipeline:
// C[2047,M] = act(Ab[2048,K] @ W[M,K]^T + bias + resF); Cf f32 / Cb bf16 out.
// Next K-tile's global loads issue right after the first barrier, in flight
// during the current tile's MFMAs (1-block/CU latency hiding).
// ---------------------------------------------------------------------------
#define LDK 72
__global__ __launch_bounds__(256, 2) void gemm_bf16(
    const unsigned short* __restrict__ Ab, const unsigned short* __restrict__ W,
    const float* __restrict__ bias, const float* resF,
    float* Cf, unsigned short* Cb, int M, int K, int relu)
{
    __shared__ unsigned short As[64][LDK];
    __shared__ unsigned short Bs[64][LDK];
    int tid = threadIdx.x;
    int wave = tid >> 6, lane = tid & 63;
    int quad = lane >> 4, l16 = lane & 15;
    int row0 = blockIdx.y << 6, col0 = blockIdx.x << 6;
    int srow = tid >> 2, scol = (tid & 3) << 4;

    f32x4 acc[4];
    #pragma unroll
    for (int i = 0; i < 4; i++) { f32x4 z = {0.f,0.f,0.f,0.f}; acc[i] = z; }

    const u16x8* ap = (const u16x8*)(Ab + (size_t)(row0 + srow) * K + scol);
    const u16x8* wp = (const u16x8*)(W + (size_t)(col0 + srow) * K + scol);
    u16x8 a0 = ap[0], a1 = ap[1];
    u16x8 b0 = wp[0], b1 = wp[1];

    for (int k0 = 0; k0 < K; k0 += 64) {
        *(u16x8*)&As[srow][scol]     = a0;
        *(u16x8*)&As[srow][scol + 8] = a1;
        *(u16x8*)&Bs[srow][scol]     = b0;
        *(u16x8*)&Bs[srow][scol + 8] = b1;
        __syncthreads();
        if (k0 + 64 < K) {               // prefetch next tile (stays in flight)
            ap += 8; wp += 8;
            a0 = ap[0]; a1 = ap[1];
            b0 = wp[0]; b1 = wp[1];
        }
        #pragma unroll
        for (int kt = 0; kt < 64; kt += 32) {
            bf16x8 af = *(bf16x8*)&As[(wave << 4) + l16][kt + (quad << 3)];
            #pragma unroll
            for (int n0 = 0; n0 < 4; n0++) {
                bf16x8 bf = *(bf16x8*)&Bs[(n0 << 4) + l16][kt + (quad << 3)];
                acc[n0] = __builtin_amdgcn_mfma_f32_16x16x32_bf16(af, bf, acc[n0], 0, 0, 0);
            }
        }
        __syncthreads();
    }
    #pragma unroll
    for (int n0 = 0; n0 < 4; n0++) {
        int col = col0 + (n0 << 4) + l16;
        if (col >= M) continue;
        float bv = bias ? bias[col] : 0.f;
        #pragma unroll
        for (int r = 0; r < 4; r++) {
            int row = row0 + (wave << 4) + (quad << 2) + r;
            if (row >= S_ROWS) continue;
            float v = acc[n0][r] + bv;
            if (resF) v += resF[(size_t)row * M + col];
            if (relu) v = fmaxf(v, 0.f);
            if (Cf) Cf[(size_t)row * M + col] = v;
            if (Cb) Cb[(size_t)row * M + col] = f2b(v);
        }
    }
}

// ---------------------------------------------------------------------------
// Fused QKV GEMM (register-prefetch) -> attention-native bf16 layouts:
//   qbh [h][q][d] (x 0.25506362 = 1/sqrt(32)*log2e), kbh [h][t][d] (+bk),
//   vbT [h][d][t].
// ---------------------------------------------------------------------------
__global__ __launch_bounds__(256, 2) void gemm_qkv(
    const unsigned short* __restrict__ Ab, const unsigned short* __restrict__ Wq,
    const unsigned short* __restrict__ Wk, const unsigned short* __restrict__ Wv,
    const float* __restrict__ bk,
    unsigned short* __restrict__ qbh, unsigned short* __restrict__ kbh,
    unsigned short* __restrict__ vbT)
{
    __shared__ unsigned short As[64][LDK];
    __shared__ unsigned short Bs[64][LDK];
    const int N = S_ROWS, K = 256;
    int tid = threadIdx.x;
    int wave = tid >> 6, lane = tid & 63;
    int quad = lane >> 4, l16 = lane & 15;
    int row0 = blockIdx.y << 6, col0 = blockIdx.x << 6;
    int mode = col0 >> 8;                 // 0=q 1=k 2=v
    int wcol0 = col0 & 255;
    const unsigned short* W = (mode == 0) ? Wq : (mode == 1) ? Wk : Wv;
    int srow = tid >> 2, scol = (tid & 3) << 4;

    f32x4 acc[4];
    #pragma unroll
    for (int i = 0; i < 4; i++) { f32x4 z = {0.f,0.f,0.f,0.f}; acc[i] = z; }

    const u16x8* ap = (const u16x8*)(Ab + (size_t)(row0 + srow) * K + scol);
    const u16x8* wp = (const u16x8*)(W + (size_t)(wcol0 + srow) * K + scol);
    u16x8 a0 = ap[0], a1 = ap[1];
    u16x8 b0 = wp[0], b1 = wp[1];

    for (int k0 = 0; k0 < K; k0 += 64) {
        *(u16x8*)&As[srow][scol]     = a0;
        *(u16x8*)&As[srow][scol + 8] = a1;
        *(u16x8*)&Bs[srow][scol]     = b0;
        *(u16x8*)&Bs[srow][scol + 8] = b1;
        __syncthreads();
        if (k0 + 64 < K) {
            ap += 8; wp += 8;
            a0 = ap[0]; a1 = ap[1];
            b0 = wp[0]; b1 = wp[1];
        }
        #pragma unroll
        for (int kt = 0; kt < 64; kt += 32) {
            bf16x8 af = *(bf16x8*)&As[(wave << 4) + l16][kt + (quad << 3)];
            #pragma unroll
            for (int n0 = 0; n0 < 4; n0++) {
                bf16x8 bf = *(bf16x8*)&Bs[(n0 << 4) + l16][kt + (quad << 3)];
                acc[n0] = __builtin_amdgcn_mfma_f32_16x16x32_bf16(af, bf, acc[n0], 0, 0, 0);
            }
        }
        __syncthreads();
    }
    #pragma unroll
    for (int n0 = 0; n0 < 4; n0++) {
        int colr = wcol0 + (n0 << 4) + l16;      // 0..255
        int hh = colr >> 5, d = colr & 31;
        int rbase = row0 + (wave << 4) + (quad << 2);
        if (mode == 2) {
            unsigned short* dst = vbT + ((size_t)hh * 32 + d) * 2048 + rbase;
            if (rbase + 3 < N) {
                u16x4 o;
                #pragma unroll
                for (int r = 0; r < 4; r++) o[r] = f2b(acc[n0][r]);
                *(u16x4*)dst = o;
            } else {
                #pragma unroll
                for (int r = 0; r < 4; r++)
                    if (rbase + r < N) dst[r] = f2b(acc[n0][r]);
            }
        } else {
            float bias = (mode == 1) ? bk[colr] : 0.f;
            unsigned short* dst = ((mode == 0) ? qbh : kbh) + (size_t)hh * 2048 * 32 + d;
            #pragma unroll
            for (int r = 0; r < 4; r++) {
                int row = rbase + r;
                if (row < N) {
                    float v = acc[n0][r] + bias;
                    if (mode == 0) v *= 0.25506362f;
                    dst[(size_t)row * 32] = f2b(v);
                }
            }
        }
    }
}

// ---------------------------------------------------------------------------
// MFMA flash attention. 1 wave = 32 queries x 1 head.
// ---------------------------------------------------------------------------
__global__ __launch_bounds__(64) void attn_mfma(
    const unsigned short* __restrict__ qbh,
    const unsigned short* __restrict__ kbh,
    const unsigned short* __restrict__ vbT,
    float* __restrict__ part_o, float* __restrict__ part_ml)
{
    int lane = threadIdx.x;
    int l31 = lane & 31, hf = lane >> 5;
    int q0 = blockIdx.x << 5;
    int h = blockIdx.y, c = blockIdx.z;
    int kstart = c * 512;
    int kend = min(kstart + 512, S_ROWS);

    const unsigned short* qp = qbh + ((size_t)h * 2048 + (q0 + l31)) * 32 + hf * 8;
    bf16x8 qf0 = *(const bf16x8*)(qp);
    bf16x8 qf1 = *(const bf16x8*)(qp + 16);

    const unsigned short* kb_h = kbh + (size_t)h * 2048 * 32;
    const unsigned short* vb_h = vbT + ((size_t)h * 32 + l31) * 2048;

    f32x16 acc = {};
    float m = -1e30f, l = 0.f;

    for (int key0 = kstart; key0 < kend; key0 += 32) {
        const unsigned short* kp = kb_h + (size_t)(key0 + l31) * 32 + hf * 8;
        bf16x8 kf0 = *(const bf16x8*)(kp);
        bf16x8 kf1 = *(const bf16x8*)(kp + 16);
        bf16x8 vf0 = *(const bf16x8*)(vb_h + key0 + hf * 8);
        bf16x8 vf1 = *(const bf16x8*)(vb_h + key0 + 16 + hf * 8);

        f32x16 sc = {};
        sc = __builtin_amdgcn_mfma_f32_32x32x16_bf16(kf0, qf0, sc, 0, 0, 0);
        sc = __builtin_amdgcn_mfma_f32_32x32x16_bf16(kf1, qf1, sc, 0, 0, 0);

        if (key0 + 32 > kend) {
            #pragma unroll
            for (int r = 0; r < 16; r++) {
                int kr = key0 + (r & 3) + 8 * (r >> 2) + 4 * hf;
                if (kr >= kend) sc[r] = -1e30f;
            }
        }
        float tmax = sc[0];
        #pragma unroll
        for (int r = 1; r < 16; r++) tmax = fmaxf(tmax, sc[r]);
        tmax = fmaxf(tmax, __shfl_xor(tmax, 32, 64));
        float mnew = fmaxf(m, tmax);
        float corr = __builtin_amdgcn_exp2f(m - mnew);
        m = mnew;
        float p[16];
        float ls = 0.f;
        #pragma unroll
        for (int r = 0; r < 16; r++) {
            p[r] = __builtin_amdgcn_exp2f(sc[r] - mnew);
            ls += p[r];
        }
        ls += __shfl_xor(ls, 32, 64);
        l = l * corr + ls;
        if (__ballot(corr != 1.0f)) {
            #pragma unroll
            for (int r = 0; r < 16; r++) acc[r] *= corr;
        }
        unsigned int pk[8];
        #pragma unroll
        for (int i = 0; i < 8; i++)
            pk[i] = __builtin_amdgcn_perm(__float_as_uint(p[2*i+1]),
                                          __float_as_uint(p[2*i]), 0x07060302u);
        unsigned int x[8];
        #pragma unroll
        for (int i = 0; i < 8; i++)
            x[i] = (unsigned int)__shfl_xor((int)pk[i], 32, 64);
        union { unsigned int u[4]; bf16x8 v; } B1, B2;
        B1.u[0] = hf ? x[2]  : pk[0];
        B1.u[1] = hf ? x[3]  : pk[1];
        B1.u[2] = hf ? pk[2] : x[0];
        B1.u[3] = hf ? pk[3] : x[1];
        B2.u[0] = hf ? x[6]  : pk[4];
        B2.u[1] = hf ? x[7]  : pk[5];
        B2.u[2] = hf ? pk[6] : x[4];
        B2.u[3] = hf ? pk[7] : x[5];
        acc = __builtin_amdgcn_mfma_f32_32x32x16_bf16(vf0, B1.v, acc, 0, 0, 0);
        acc = __builtin_amdgcn_mfma_f32_32x32x16_bf16(vf1, B2.v, acc, 0, 0, 0);
    }

    int q = q0 + l31;
    size_t ob_base = ((size_t)(c * NHEADS + h) * 2048 + q) * 32;
    #pragma unroll
    for (int g = 0; g < 4; g++) {
        float4 o4;
        o4.x = acc[4*g]; o4.y = acc[4*g+1]; o4.z = acc[4*g+2]; o4.w = acc[4*g+3];
        *(float4*)(part_o + ob_base + 4*hf + 8*g) = o4;
    }
    if (!hf) {
        size_t mlb = ((size_t)(c * NHEADS + h) * 2048 + q) * 2;
        part_ml[mlb] = m; part_ml[mlb + 1] = l;
    }
}

__global__ __launch_bounds__(256) void attn_combine(
    const float* __restrict__ part_o, const float* __restrict__ part_ml,
    unsigned short* __restrict__ obb)
{
    int idx = blockIdx.x * 256 + threadIdx.x;
    if (idx >= S_ROWS * NHEADS) return;
    int h = idx & 7, q = idx >> 3;
    float m = -1e30f;
    #pragma unroll
    for (int c = 0; c < KCHUNKS; c++)
        m = fmaxf(m, part_ml[((size_t)(c * NHEADS + h) * 2048 + q) * 2]);
    float l = 0.f;
    float num[32];
    #pragma unroll
    for (int d = 0; d < 32; d++) num[d] = 0.f;
    #pragma unroll
    for (int c = 0; c < KCHUNKS; c++) {
        size_t rec = (size_t)(c * NHEADS + h) * 2048 + q;
        float2 mlv = *(const float2*)(part_ml + rec * 2);
        float w = __builtin_amdgcn_exp2f(mlv.x - m);
        l += mlv.y * w;
        const float* po = part_o + rec * 32;
        #pragma unroll
        for (int d4 = 0; d4 < 8; d4++) {
            float4 o4 = *(const float4*)(po + 4 * d4);
            num[4*d4+0] = fmaf(o4.x, w, num[4*d4+0]);
            num[4*d4+1] = fmaf(o4.y, w, num[4*d4+1]);
            num[4*d4+2] = fmaf(o4.z, w, num[4*d4+2]);
            num[4*d4+3] = fmaf(o4.w, w, num[4*d4+3]);
        }
    }
    float inv = 1.f / l;
    unsigned short* op = obb + (size_t)q * DIM + h * DH;
    #pragma unroll
    for (int g = 0; g < 4; g++) {
        u16x8 o8;
        #pragma unroll
        for (int j = 0; j < 8; j++) o8[j] = f2b(num[8*g + j] * inv);
        *(u16x8*)(op + 8*g) = o8;
    }
}

// ---------------------------------------------------------------------------
// RQS spline, register-only, fused logdet reduce + atomicAdd to out[6144].
// ---------------------------------------------------------------------------
__global__ __launch_bounds__(256) void spline_kernel(const float* __restrict__ pos,
    const float* __restrict__ params, float* __restrict__ out)
{
    int r = blockIdx.x * 256 + threadIdx.x;
    float ld = 0.f;
    if (r < S_ROWS) {
        const float* p = params + (size_t)r * AFF_OUT;
        float x = pos[(r + 1) * 3 + 2];
        float xc = fminf(fmaxf(x, 0.f), 1.f);

        float mw = -1e30f, mh = -1e30f;
        #pragma unroll
        for (int j = 0; j < NBINS; j++) {
            mw = fmaxf(mw, p[j]);
            mh = fmaxf(mh, p[NBINS + j]);
        }
        float sw = 0.f, sh = 0.f;
        #pragma unroll
        for (int j = 0; j < NBINS; j++) {
            sw += __expf(p[j] - mw);
            sh += __expf(p[NBINS + j] - mh);
        }
        const float span = 1.0f - NBINS * 1e-4f;
        float scw = span / sw, sch = span / sh;

        float cumw = 0.f, cumh = 0.f;
        float xk = 0.f, yk = 0.f, wk = 0.f, hk = 0.f;
        int k = 0;
        #pragma unroll
        for (int j = 0; j < NBINS; j++) {
            float wj = __expf(p[j] - mw) * scw + 1e-4f;
            float hj = __expf(p[NBINS + j] - mh) * sch + 1e-4f;
            if (xc >= cumw) { k = j; xk = cumw; yk = cumh; wk = wj; hk = hj; }
            cumw += wj; cumh += hj;
        }
        float offset = logf(expm1f(0.9999f));
        float t0 = p[2 * NBINS + k] + offset;
        float t1 = ((k == NBINS - 1) ? p[2 * NBINS] : p[2 * NBINS + k + 1]) + offset;
        float dk  = ((t0 > 15.f) ? t0 : log1pf(__expf(t0))) + 1e-4f;
        float dk1 = ((t1 > 15.f) ? t1 : log1pf(__expf(t1))) + 1e-4f;

        float sl = hk / wk;
        float z = (xc - xk) / wk;
        float z1 = 1.f - z;
        float den = sl + (dk1 + dk - 2.f * sl) * z * z1;
        float y = yk + hk * (sl * z * z + dk * z * z1) / den;
        float ldv = 2.f * logf(sl)
                  + logf(dk1 * z * z + 2.f * sl * z * z1 + dk * z1 * z1)
                  - 2.f * logf(den);
        bool inside = (x >= 0.f) && (x <= 1.f);
        y = inside ? y : x;
        ld = inside ? ldv : 0.f;
        out[(r + 1) * 3 + 2] = y;
    }
    __shared__ float sh[256];
    int tid = threadIdx.x;
    sh[tid] = ld;
    __syncthreads();
    for (int st = 128; st > 0; st >>= 1) {
        if (tid < st) sh[tid] += sh[tid + st];
        __syncthreads();
    }
    if (tid == 0) atomicAdd(&out[6144], sh[0]);
}

// ---------------------------------------------------------------------------
extern "C" void kernel_launch(void* const* d_in, const int* in_sizes, int n_in,
                              void* d_out, int out_size, void* d_ws, size_t ws_size,
                              hipStream_t stream)
{
    const float* pos   = (const float*)d_in[0];
    const float* scale = (const float*)d_in[1];
    const float* press = (const float*)d_in[2];
    const float* temp  = (const float*)d_in[3];
    const float* e_w0  = (const float*)d_in[4];
    const float* e_b0  = (const float*)d_in[5];
    const float* e_w1  = (const float*)d_in[6];
    const float* e_b1  = (const float*)d_in[7];
    const float* e_w2  = (const float*)d_in[8];
    const float* e_b2  = (const float*)d_in[9];
    const float* Wq    = (const float*)d_in[10];
    const float* Wk    = (const float*)d_in[11];
    const float* bk    = (const float*)d_in[12];
    const float* Wv    = (const float*)d_in[13];
    const float* Wo    = (const float*)d_in[14];
    const float* bo    = (const float*)d_in[15];
    const float* mw0   = (const float*)d_in[16];
    const float* mb0   = (const float*)d_in[17];
    const float* mw1   = (const float*)d_in[18];
    const float* mb1   = (const float*)d_in[19];
    const float* mw2   = (const float*)d_in[20];
    const float* mb2   = (const float*)d_in[21];
    const float* a_w0  = (const float*)d_in[22];
    const float* a_b0  = (const float*)d_in[23];
    const float* a_w1  = (const float*)d_in[24];
    const float* a_b1  = (const float*)d_in[25];
    const float* a_w2  = (const float*)d_in[26];
    const float* a_b2  = (const float*)d_in[27];
    float* out = (float*)d_out;

    // bf16 weight region offsets (u16 elements): [ew0p | main segments]
    enum { OFF_EW0 = 0,
           OFF_EW1 = 32768 + 0,       OFF_EW2 = 32768 + 262144,
           OFF_WQ  = 32768 + 393216,  OFF_WK  = 32768 + 655360,
           OFF_WV  = 32768 + 917504,  OFF_WO  = 32768 + 1179648,
           OFF_MW0 = 32768 + 1441792, OFF_MW1 = 32768 + 1966080,
           OFF_MW2 = 32768 + 3014656, OFF_AW0 = 32768 + 3538944,
           OFF_AW1 = 32768 + 3670016, OFF_AW2 = 32768 + 3932160 };
    const size_t WB_U16 = (size_t)EW0P_N + W_MAIN;   // 3990016

    float* ws = (float*)d_ws;
    size_t off = 0;
    float* hbuf = ws + off; off += 2048 * 256;             // f32 residual stream
    float* pr   = ws + off; off += 2048 * 64;              // spline params f32
    unsigned short* wbp   = (unsigned short*)(ws + off); off += WB_U16 / 2;
    unsigned short* cond  = (unsigned short*)(ws + off); off += 2048 * 64 / 2;
    unsigned short* t1b   = (unsigned short*)(ws + off); off += 2048 * 512 / 2;
    unsigned short* t2b   = (unsigned short*)(ws + off); off += 2048 * 512 / 2;
    unsigned short* hb    = (unsigned short*)(ws + off); off += 2048 * 256 / 2;
    unsigned short* obb   = (unsigned short*)(ws + off); off += 2048 * 256 / 2;
    unsigned short* qbh   = (unsigned short*)(ws + off); off += NHEADS * 2048 * 32 / 2;
    unsigned short* kbh   = (unsigned short*)(ws + off); off += NHEADS * 2048 * 32 / 2;
    unsigned short* vbT   = (unsigned short*)(ws + off); off += NHEADS * 2048 * 32 / 2;
    float* part_o  = ws + off; off += (size_t)KCHUNKS * NHEADS * 2048 * 32;
    float* part_ml = ws + off; off += (size_t)KCHUNKS * NHEADS * 2048 * 2;
    (void)ws_size;

    dim3 b256(256);
    hipLaunchKernelGGL(setup_kernel, dim3(1024), b256, 0, stream,
                       pos, scale, press, temp, e_w0,
                       e_w1, e_w2, Wq, Wk, Wv, Wo, mw0, mw1, mw2,
                       a_w0, a_w1, a_w2, wbp, cond, out);

    auto gemm = [&](const unsigned short* A, const unsigned short* W,
                    const float* bias, const float* resF, float* Cf,
                    unsigned short* Cb, int M, int K, int relu) {
        dim3 grid((M + 63) / 64, 32);
        hipLaunchKernelGGL(gemm_bf16, grid, dim3(256), 0, stream,
                           A, W, bias, resF, Cf, Cb, M, K, relu);
    };

    // embedding MLP: 35(->64) -> 512 -> 512 -> 256
    gemm(cond, wbp + OFF_EW0, e_b0, nullptr, nullptr, t1b, 512, 64, 1);
    gemm(t1b,  wbp + OFF_EW1, e_b1, nullptr, nullptr, t2b, 512, 512, 1);
    gemm(t2b,  wbp + OFF_EW2, e_b2, nullptr, hbuf, hb, 256, 512, 0);

    for (int l = 0; l < 4; l++) {
        hipLaunchKernelGGL(gemm_qkv, dim3(12, 32), b256, 0, stream,
                           hb, wbp + OFF_WQ + l * 65536, wbp + OFF_WK + l * 65536,
                           wbp + OFF_WV + l * 65536, bk + l * 256, qbh, kbh, vbT);
        hipLaunchKernelGGL(attn_mfma, dim3(64, NHEADS, KCHUNKS), dim3(64), 0, stream,
                           qbh, kbh, vbT, part_o, part_ml);
        hipLaunchKernelGGL(attn_combine, dim3((S_ROWS * NHEADS + 255) / 256), b256,
                           0, stream, part_o, part_ml, obb);
        gemm(obb, wbp + OFF_WO + l * 65536, bo + l * 256, hbuf, hbuf, hb, 256, 256, 0);
        gemm(hb,  wbp + OFF_MW0 + l * 131072, mb0 + l * 512, nullptr, nullptr, t1b, 512, 256, 1);
        gemm(t1b, wbp + OFF_MW1 + l * 262144, mb1 + l * 512, nullptr, nullptr, t2b, 512, 512, 1);
        gemm(t2b, wbp + OFF_MW2 + l * 131072, mb2 + l * 256, hbuf, hbuf, hb, 256, 512, 0);
    }

    // affine-param MLP: 256 -> 512 -> 512 -> 49
    gemm(hb,  wbp + OFF_AW0, a_b0, nullptr, nullptr, t1b, 512, 256, 1);
    gemm(t1b, wbp + OFF_AW1, a_b1, nullptr, nullptr, t2b, 512, 512, 1);
    gemm(t2b, wbp + OFF_AW2, a_b2, nullptr, pr, nullptr, AFF_OUT, 512, 0);

    hipLaunchKernelGGL(spline_kernel, dim3(8), b256, 0, stream, pos, pr, out);
}